// Round 7
// baseline (920.944 us; speedup 1.0000x reference)
//
#include <hip/hip_runtime.h>

typedef __bf16 bf16x8 __attribute__((ext_vector_type(8)));
typedef float f32x16 __attribute__((ext_vector_type(16)));
typedef unsigned short ushort8 __attribute__((ext_vector_type(8)));

// ---------- helpers ----------
__device__ __forceinline__ float gelu_exact(float x) {
    return 0.5f * x * (1.0f + erff(x * 0.70710678118654752440f));
}

// async global->LDS, 16B per lane; dest is wave-uniform base, HW adds lane*16
__device__ __forceinline__ void gload_lds16(const void* g, void* l) {
    __builtin_amdgcn_global_load_lds(
        (const __attribute__((address_space(1))) unsigned int*)g,
        (__attribute__((address_space(3))) unsigned int*)l, 16, 0, 0);
}

#define MFMA(a, b, c) __builtin_amdgcn_mfma_f32_32x32x16_bf16((a), (b), (c), 0, 0, 0)

// =====================================================================
// Packed operand layout (bf16 hi/lo, MFMA-fragment-linear):
//   A-pack for [M][256]: slot s = (rb*16 + kb)*64 + lane, 8 ushorts each.
//     lane's elems = A[rb*32 + (lane&31)][kb*16 + (lane>>5)*8 + i], i=0..7
//   B-pack for W[K][256]: slot = (nb*KB + kb)*64 + lane, KB = K/16.
//     lane's elems = W[kb*16 + (lane>>5)*8 + i][nb*32 + (lane&31)]
//   LDS A/pack region (32 rows x 256 k, hi/lo): byte(row,k) =
//     hl*16384 + (k>>4)*1024 + ((k>>3)&1)*512 + row*16 + (k&7)*2
//   LDS total 49664 B: pack 32768 + per-wave tbuf 4 x 32*33*4 (pad-33, conflict-free)
// =====================================================================

// ================= CSR build =================
__global__ __launch_bounds__(256) void count_kernel(
    const int* __restrict__ tgt, const int* __restrict__ src,
    int* __restrict__ cnt_i, int* __restrict__ cnt_a, int E)
{
    int e = blockIdx.x * 256 + threadIdx.x;
    if (e < E) {
        atomicAdd(&cnt_i[tgt[e]], 1);
        atomicAdd(&cnt_a[src[e]], 1);
    }
}

__global__ __launch_bounds__(256) void scan_block(
    const int* __restrict__ cnt, int* __restrict__ offs, int* __restrict__ bsum, int N)
{
    __shared__ int s[256];
    int i = blockIdx.x * 256 + threadIdx.x;
    int v = (i < N) ? cnt[i] : 0;
    s[threadIdx.x] = v;
    __syncthreads();
    for (int d = 1; d < 256; d <<= 1) {
        int t = (threadIdx.x >= d) ? s[threadIdx.x - d] : 0;
        __syncthreads();
        s[threadIdx.x] += t;
        __syncthreads();
    }
    if (i < N) offs[i] = s[threadIdx.x] - v;   // exclusive
    if (threadIdx.x == 255) bsum[blockIdx.x] = s[255];
}

__global__ __launch_bounds__(256) void scan_bsum(int* __restrict__ bsum, int nb)
{
    __shared__ int s[256];
    int v = (threadIdx.x < nb) ? bsum[threadIdx.x] : 0;
    s[threadIdx.x] = v;
    __syncthreads();
    for (int d = 1; d < 256; d <<= 1) {
        int t = (threadIdx.x >= d) ? s[threadIdx.x - d] : 0;
        __syncthreads();
        s[threadIdx.x] += t;
        __syncthreads();
    }
    if (threadIdx.x < nb) bsum[threadIdx.x] = s[threadIdx.x] - v;  // exclusive
}

__global__ __launch_bounds__(256) void add_offs(
    int* __restrict__ offs, int* __restrict__ cursor,
    const int* __restrict__ bsum, int N, int E)
{
    int i = blockIdx.x * 256 + threadIdx.x;
    if (i < N) {
        int f = offs[i] + bsum[blockIdx.x];
        offs[i] = f;
        cursor[i] = f;
    }
    if (i == 0) offs[N] = E;
}

// materialize CSR-ordered source index + log(nw)
__global__ __launch_bounds__(256) void fill_kernel(
    const int* __restrict__ tgt, const int* __restrict__ src,
    const float* __restrict__ nw_i, const float* __restrict__ nw_a,
    int* __restrict__ cur_i, int* __restrict__ cur_a,
    int* __restrict__ src_i, float* __restrict__ lw_i,
    int* __restrict__ src_a, float* __restrict__ lw_a, int E)
{
    int e = blockIdx.x * 256 + threadIdx.x;
    if (e < E) {
        int t = tgt[e], s = src[e];
        float li = logf(fmaxf(nw_i[e], 1e-10f));
        float la = logf(fmaxf(nw_a[e], 1e-10f));
        int p = atomicAdd(&cur_i[t], 1);
        src_i[p] = s; lw_i[p] = li;
        int q = atomicAdd(&cur_a[s], 1);
        src_a[q] = t; lw_a[q] = la;
    }
}

// ================= weight prep: f32 W[K][256] -> packed B fragments =================
struct PrepArgs {
    const float* src[7];
    unsigned short* hi[7];
    unsigned short* lo[7];
    int K[7];
    int off[8];   // slot offsets; slots per matrix = (K/16)*8*64
};

__global__ __launch_bounds__(256) void prep_w(PrepArgs a)
{
    int s = blockIdx.x * 256 + threadIdx.x;
    if (s >= a.off[7]) return;
    int m = 0;
    #pragma unroll
    for (int i = 0; i < 6; ++i) m += (s >= a.off[i + 1]) ? 1 : 0;
    int sl = s - a.off[m];
    int KB = a.K[m] >> 4;
    int l  = sl & 63;
    int kb = (sl >> 6) % KB;
    int nb = (sl >> 6) / KB;
    int n  = nb * 32 + (l & 31);
    int k0 = kb * 16 + ((l >> 5) << 3);
    ushort8 hh, ll;
    #pragma unroll
    for (int i = 0; i < 8; ++i) {
        float x = a.src[m][(size_t)(k0 + i) * 256 + n];
        __bf16 h = (__bf16)x;
        hh[i] = __builtin_bit_cast(unsigned short, h);
        ll[i] = __builtin_bit_cast(unsigned short, (__bf16)(x - (float)h));
    }
    *(ushort8*)(a.hi[m] + (size_t)sl * 8) = hh;
    *(ushort8*)(a.lo[m] + (size_t)sl * 8) = ll;
}

// ================= row pack: f32 X[M][256] -> packed A fragments =================
__global__ __launch_bounds__(256) void pack_rows(
    const float* __restrict__ X, unsigned short* __restrict__ Ph,
    unsigned short* __restrict__ Pl, int M, int RB)
{
    int s = blockIdx.x * 256 + threadIdx.x;
    int total = RB * 16 * 64;
    if (s >= total) return;
    int l  = s & 63;
    int kb = (s >> 6) & 15;
    int rb = s >> 10;
    int row = min(rb * 32 + (l & 31), M - 1);
    int k0  = kb * 16 + ((l >> 5) << 3);
    const float* p = X + (size_t)row * 256 + k0;
    float4 f0 = *(const float4*)p;
    float4 f1 = *(const float4*)(p + 4);
    float xs[8] = {f0.x, f0.y, f0.z, f0.w, f1.x, f1.y, f1.z, f1.w};
    ushort8 hh, ll;
    #pragma unroll
    for (int i = 0; i < 8; ++i) {
        __bf16 h = (__bf16)xs[i];
        hh[i] = __builtin_bit_cast(unsigned short, h);
        ll[i] = __builtin_bit_cast(unsigned short, (__bf16)(xs[i] - (float)h));
    }
    *(ushort8*)(Ph + (size_t)s * 8) = hh;
    *(ushort8*)(Pl + (size_t)s * 8) = ll;
}

// ================= fused per-target attention (unchanged, proven) =================
__global__ __launch_bounds__(256) void fused_attn(
    const float* __restrict__ Q, const float* __restrict__ Kk, const float* __restrict__ V,
    const int* __restrict__ offs, const int* __restrict__ srcs,
    const float* __restrict__ lws,
    float* __restrict__ scbuf, unsigned short* __restrict__ msgH,
    unsigned short* __restrict__ msgL, int T)
{
    int w = blockIdx.x * 4 + (threadIdx.x >> 6);
    int lane = threadIdx.x & 63;
    if (w >= T) return;
    int t = w;
    int beg = offs[t], end = offs[t + 1];
    int h = lane >> 4;

    float4 q = *(const float4*)(Q + (size_t)t * 256 + lane * 4);

    // ---- pass 1: scores + running max ----
    float mx = 0.f;   // 0-init matches torch scatter amax include_self with zeros
    {
        int sN = 0; float lC = 0.f, lN = 0.f;
        float4 k0 = make_float4(0.f, 0.f, 0.f, 0.f);
        if (beg < end) {
            int s0 = srcs[beg];
            lC = lws[beg];
            k0 = *(const float4*)(Kk + (size_t)s0 * 256 + lane * 4);
        }
        if (beg + 1 < end) { sN = srcs[beg + 1]; lN = lws[beg + 1]; }
        for (int j = beg; j < end; ++j) {
            int sNN = 0; float lNN = 0.f;
            if (j + 2 < end) { sNN = srcs[j + 2]; lNN = lws[j + 2]; }
            float4 k1 = k0;
            if (j + 1 < end) k1 = *(const float4*)(Kk + (size_t)sN * 256 + lane * 4);
            float d = q.x * k0.x + q.y * k0.y + q.z * k0.z + q.w * k0.w;
            d += __shfl_xor(d, 1);
            d += __shfl_xor(d, 2);
            d += __shfl_xor(d, 4);
            d += __shfl_xor(d, 8);
            float sc = d * 0.125f + lC;
            if ((lane & 15) == 0) scbuf[(size_t)j * 4 + h] = sc;
            mx = fmaxf(mx, sc);
            k0 = k1; lC = lN; sN = sNN; lN = lNN;
        }
    }

    // ---- pass 2: exp/sum + ex*V accumulate ----
    float sum = 0.f;
    float4 macc = make_float4(0.f, 0.f, 0.f, 0.f);
    {
        int sN = 0; float scC = 0.f, scN = 0.f;
        float4 v0 = make_float4(0.f, 0.f, 0.f, 0.f);
        if (beg < end) {
            int s0 = srcs[beg];
            scC = scbuf[(size_t)beg * 4 + h];
            v0 = *(const float4*)(V + (size_t)s0 * 256 + lane * 4);
        }
        if (beg + 1 < end) { sN = srcs[beg + 1]; scN = scbuf[(size_t)(beg + 1) * 4 + h]; }
        for (int j = beg; j < end; ++j) {
            int sNN = 0; float scNN = 0.f;
            if (j + 2 < end) { sNN = srcs[j + 2]; scNN = scbuf[(size_t)(j + 2) * 4 + h]; }
            float4 v1 = v0;
            if (j + 1 < end) v1 = *(const float4*)(V + (size_t)sN * 256 + lane * 4);
            float ex = expf(scC - mx);
            sum += ex;
            macc.x += ex * v0.x; macc.y += ex * v0.y;
            macc.z += ex * v0.z; macc.w += ex * v0.w;
            v0 = v1; scC = scN; sN = sNN; scN = scNN;
        }
    }
    float inv = 1.f / (sum + 1e-10f);
    float vals[4] = {macc.x * inv, macc.y * inv, macc.z * inv, macc.w * inv};
    unsigned short hs[4], ls[4];
    #pragma unroll
    for (int i = 0; i < 4; ++i) {
        __bf16 hh = (__bf16)vals[i];
        hs[i] = __builtin_bit_cast(unsigned short, hh);
        ls[i] = __builtin_bit_cast(unsigned short, (__bf16)(vals[i] - (float)hh));
    }
    // packed slot: cols c = 4*lane..4*lane+3 of row t
    size_t base = (((size_t)(t >> 5) * 16 + (lane >> 2)) * 64 + ((lane >> 1) & 1) * 32 + (t & 31)) * 8
                + ((lane & 1) << 2);
    *(ushort4*)(msgH + base) = make_ushort4(hs[0], hs[1], hs[2], hs[3]);
    *(ushort4*)(msgL + base) = make_ushort4(ls[0], ls[1], ls[2], ls[3]);
}

// ================= fused node kernel =================
// Block = 32 rows x 256 cols; 4 waves, wave w owns col-subtiles nb0=2w, 2w+1.
// MODE 0: stage 32-row h-pack slab ONCE into LDS, then 5 full-K loops off LDS:
//   K->HBM, Q->HBM, t->packed-in-LDS, M->packed-in-LDS, V->HBM.
// MODE 1: streamed counted-vmcnt pipeline over K=512 (concat h|msg) -> hid;
//   pack hid to LDS; out-loop reads pack, writes final output.
// gemm_lds: depth-4 static-ring B prefetch (covers L2 latency under 6 MFMA/kb).
// pack path: per-wave pad-33 f32 tbuf transpose -> ds_write_b128 pack (0 conflicts).
template<int MODE>
__global__ __launch_bounds__(256, 3) void fused_node(
    const unsigned short* __restrict__ Ah, const unsigned short* __restrict__ Al,
    const unsigned short* __restrict__ A2h, const unsigned short* __restrict__ A2l,
    const unsigned short* __restrict__ B1h, const unsigned short* __restrict__ B1l,  // Wk | u_w1
    const unsigned short* __restrict__ B2h, const unsigned short* __restrict__ B2l,  // Wq | u_w2
    const unsigned short* __restrict__ B3h, const unsigned short* __restrict__ B3l,  // m_w1
    const unsigned short* __restrict__ B4h, const unsigned short* __restrict__ B4l,  // m_w2
    const unsigned short* __restrict__ B5h, const unsigned short* __restrict__ B5l,  // Wv
    const float* __restrict__ bias1, const float* __restrict__ bias2,
    int M,
    float* __restrict__ O1, float* __restrict__ O2, float* __restrict__ O3)
{
    extern __shared__ char smem[];
    const int lane = threadIdx.x & 63;
    const int w = threadIdx.x >> 6;
    const int nb0 = w * 2;
    const int rb = blockIdx.x;
    float* tb = (float*)(smem + 32768 + w * 4224);   // per-wave 32 x 33 f32

    auto loadB4 = [&](ushort8* dst, const unsigned short* BH, const unsigned short* BL,
                      int KBw, int kb) {
        size_t t0 = ((size_t)((nb0 + 0) * KBw + kb) * 64 + lane) * 8;
        size_t t1 = ((size_t)((nb0 + 1) * KBw + kb) * 64 + lane) * 8;
        dst[0] = *(const ushort8*)(BH + t0);
        dst[1] = *(const ushort8*)(BL + t0);
        dst[2] = *(const ushort8*)(BH + t1);
        dst[3] = *(const ushort8*)(BL + t1);
    };

    // full-K=256 GEMM off the LDS A/pack region; depth-4 B prefetch ring
    auto gemm_lds = [&](const unsigned short* BH, const unsigned short* BL,
                        f32x16& A0, f32x16& A1) {
        ushort8 B[4][4];
        #pragma unroll
        for (int p = 0; p < 4; ++p) loadB4(B[p], BH, BL, 16, p);
        #pragma unroll
        for (int kb = 0; kb < 16; ++kb) {
            bf16x8 ah  = __builtin_bit_cast(bf16x8, *(const ushort8*)(smem + kb * 1024 + lane * 16));
            bf16x8 alo = __builtin_bit_cast(bf16x8, *(const ushort8*)(smem + 16384 + kb * 1024 + lane * 16));
            bf16x8 b0h = __builtin_bit_cast(bf16x8, B[kb & 3][0]);
            bf16x8 b0l = __builtin_bit_cast(bf16x8, B[kb & 3][1]);
            bf16x8 c1h = __builtin_bit_cast(bf16x8, B[kb & 3][2]);
            bf16x8 c1l = __builtin_bit_cast(bf16x8, B[kb & 3][3]);
            A0 = MFMA(ah, b0h, A0); A0 = MFMA(ah, b0l, A0); A0 = MFMA(alo, b0h, A0);
            A1 = MFMA(ah, c1h, A1); A1 = MFMA(ah, c1l, A1); A1 = MFMA(alo, c1h, A1);
            if (kb + 4 < 16) loadB4(B[kb & 3], BH, BL, 16, kb + 4);
        }
    };

    // C/D layout: col = lane&31, row = (r&3) + 8*(r>>2) + 4*(lane>>5)
    auto store_f32 = [&](const f32x16& A0, const f32x16& A1, const float* bias, int act,
                         float* Out) {
        #pragma unroll
        for (int nt = 0; nt < 2; ++nt) {
            const f32x16& a = nt ? A1 : A0;
            int n = (nb0 + nt) * 32 + (lane & 31);
            float bv = bias ? bias[n] : 0.f;
            #pragma unroll
            for (int r = 0; r < 16; ++r) {
                int row = rb * 32 + (r & 3) + ((r >> 2) << 3) + ((lane >> 5) << 2);
                if (row < M) {
                    float v = a[r] + bv;
                    if (act) v = gelu_exact(v);
                    Out[(size_t)row * 256 + n] = v;
                }
            }
        }
    };

    // bias + GELU + hi/lo split into pack region, via per-wave pad-33 tbuf transpose
    auto pack_to_lds = [&](const f32x16& A0, const f32x16& A1, const float* bias) {
        #pragma unroll
        for (int nt = 0; nt < 2; ++nt) {
            const f32x16& a = nt ? A1 : A0;
            int nloc = lane & 31;
            float bv = bias[(nb0 + nt) * 32 + nloc];
            #pragma unroll
            for (int r = 0; r < 16; ++r) {
                int m = (r & 3) + ((r >> 2) << 3) + ((lane >> 5) << 2);
                tb[m * 33 + nloc] = gelu_exact(a[r] + bv);
            }
            asm volatile("s_waitcnt lgkmcnt(0)" ::: "memory");
            #pragma unroll
            for (int qq = 0; qq < 2; ++qq) {
                int c0 = ((lane >> 5) << 3) + (qq << 4);   // local col block 0,8,16,24
                int m2 = lane & 31;
                float vs[8];
                #pragma unroll
                for (int i = 0; i < 8; ++i) vs[i] = tb[m2 * 33 + c0 + i];
                ushort8 hh, ll;
                #pragma unroll
                for (int i = 0; i < 8; ++i) {
                    __bf16 hb = (__bf16)vs[i];
                    hh[i] = __builtin_bit_cast(unsigned short, hb);
                    ll[i] = __builtin_bit_cast(unsigned short, (__bf16)(vs[i] - (float)hb));
                }
                int ng = (nb0 + nt) * 32 + c0;   // global col of first elem
                char* dsth = smem + (ng >> 4) * 1024 + ((ng >> 3) & 1) * 512 + m2 * 16;
                *(ushort8*)dsth = hh;
                *(ushort8*)(dsth + 16384) = ll;
            }
            asm volatile("s_waitcnt lgkmcnt(0)" ::: "memory");  // tb reuse (same wave)
        }
    };

    if constexpr (MODE == 0) {
        // ---- one-shot stage of the 32-row h slab (32 KB) ----
        #pragma unroll
        for (int i = 0; i < 8; ++i) {
            int u = w * 8 + i, hl = u >> 4, kb = u & 15;
            const unsigned short* srcp = hl ? Al : Ah;
            const unsigned short* g = srcp + ((size_t)(rb * 16 + kb) * 64 + lane) * 8;
            gload_lds16(g, smem + hl * 16384 + kb * 1024);
        }
        asm volatile("s_waitcnt vmcnt(0)" ::: "memory");
        __builtin_amdgcn_s_barrier();

        { f32x16 a0 = {}, a1 = {}; gemm_lds(B1h, B1l, a0, a1);
          store_f32(a0, a1, nullptr, 0, O1); }                    // K = h@Wk
        { f32x16 a0 = {}, a1 = {}; gemm_lds(B2h, B2l, a0, a1);
          store_f32(a0, a1, nullptr, 0, O2); }                    // Q = h@Wq
        f32x16 t0 = {}, t1 = {};
        gemm_lds(B3h, B3l, t0, t1);                               // t = h@m_w1
        __syncthreads();                                          // all A reads done
        pack_to_lds(t0, t1, bias1);                               // gelu(t+b1) -> LDS
        __syncthreads();
        f32x16 m0 = {}, m1 = {};
        gemm_lds(B4h, B4l, m0, m1);                               // M = t@m_w2
        __syncthreads();
        pack_to_lds(m0, m1, bias2);                               // gelu(M+b2) -> LDS
        __syncthreads();
        { f32x16 a0 = {}, a1 = {}; gemm_lds(B5h, B5l, a0, a1);
          store_f32(a0, a1, nullptr, 0, O3); }                    // V = M@Wv
    } else {
        // ---- phase 2: streamed hid over K=512 (counted-vmcnt, 3-buffer) ----
        auto stage_one = [&](int bufn, int st, int u) {
            int hl = u >> 2, kb = u & 3;
            int kbg = st * 4 + kb;
            const unsigned short* srcp; int kba = kbg;
            if (kbg >= 16) { kba = kbg - 16; srcp = hl ? A2l : A2h; }
            else           { srcp = hl ? Al : Ah; }
            const unsigned short* g = srcp + ((size_t)(rb * 16 + kba) * 64 + lane) * 8;
            gload_lds16(g, smem + bufn * 8192 + (hl * 4 + kb) * 1024);
        };
        stage_one(0, 0, w * 2); stage_one(0, 0, w * 2 + 1);
        stage_one(1, 1, w * 2); stage_one(1, 1, w * 2 + 1);
        asm volatile("s_waitcnt vmcnt(2)" ::: "memory");
        __builtin_amdgcn_s_barrier();

        f32x16 h0 = {}, h1 = {};
        for (int st = 0; st < 8; ++st) {
            if (st) {
                // per iter: 16 B-loads + 2 staging = 18 newer than stage st's loads
                asm volatile("s_waitcnt vmcnt(18)" ::: "memory");
                __builtin_amdgcn_s_barrier();
            }
            const int buf = st % 3;
            ushort8 Breg[4][4];
            #pragma unroll
            for (int kb = 0; kb < 4; ++kb) loadB4(Breg[kb], B1h, B1l, 32, st * 4 + kb);
            {
                int bufn = (st + 2) % 3;
                int stc = (st + 2 < 8) ? (st + 2) : 7;   // tail: harmless reload
                stage_one(bufn, stc, w * 2);
                stage_one(bufn, stc, w * 2 + 1);
            }
            #pragma unroll
            for (int kb = 0; kb < 4; ++kb) {
                bf16x8 ah  = __builtin_bit_cast(bf16x8,
                    *(const ushort8*)(smem + buf * 8192 + kb * 1024 + lane * 16));
                bf16x8 alo = __builtin_bit_cast(bf16x8,
                    *(const ushort8*)(smem + buf * 8192 + (4 + kb) * 1024 + lane * 16));
                bf16x8 b0h = __builtin_bit_cast(bf16x8, Breg[kb][0]);
                bf16x8 b0l = __builtin_bit_cast(bf16x8, Breg[kb][1]);
                bf16x8 c1h = __builtin_bit_cast(bf16x8, Breg[kb][2]);
                bf16x8 c1l = __builtin_bit_cast(bf16x8, Breg[kb][3]);
                h0 = MFMA(ah, b0h, h0); h0 = MFMA(ah, b0l, h0); h0 = MFMA(alo, b0h, h0);
                h1 = MFMA(ah, c1h, h1); h1 = MFMA(ah, c1l, h1); h1 = MFMA(alo, c1h, h1);
            }
        }
        asm volatile("s_waitcnt vmcnt(0)" ::: "memory");   // drain stray prefetches
        __builtin_amdgcn_s_barrier();

        pack_to_lds(h0, h1, bias1);                        // gelu(hid+u_b1) -> LDS
        __syncthreads();
        { f32x16 o0 = {}, o1 = {}; gemm_lds(B2h, B2l, o0, o1);
          store_f32(o0, o1, bias2, 1, O3); }               // out = gelu(hid@u_w2+u_b2)
    }
}

// ================= host =================
extern "C" void kernel_launch(void* const* d_in, const int* in_sizes, int n_in,
                              void* d_out, int out_size, void* d_ws, size_t ws_size,
                              hipStream_t stream) {
    const float* inv_h    = (const float*)d_in[0];
    const float* asset_h  = (const float*)d_in[1];
    const float* inv_nw   = (const float*)d_in[2];
    const float* asset_nw = (const float*)d_in[3];
    const float* m_w1 = (const float*)d_in[4];
    const float* m_b1 = (const float*)d_in[5];
    const float* m_w2 = (const float*)d_in[6];
    const float* m_b2 = (const float*)d_in[7];
    const float* Wq   = (const float*)d_in[8];
    const float* Wk   = (const float*)d_in[9];
    const float* Wv   = (const float*)d_in[10];
    const float* u_w1 = (const float*)d_in[11];
    const float* u_b1 = (const float*)d_in[12];
    const float* u_w2 = (const float*)d_in[13];
    const float* u_b2 = (const float*)d_in[14];
    const int* etgt  = (const int*)d_in[15];
    const int* esrc  = (const int*)d_in[16];

    const int I = in_sizes[0] / 256;
    const int A = in_sizes[1] / 256;
    const int E = in_sizes[15];
    const int RBI = (I + 31) >> 5;
    const int RBA = (A + 31) >> 5;

    float* out_inv   = (float*)d_out;
    float* out_asset = (float*)d_out + (size_t)I * 256;

    char* wsp = (char*)d_ws;
    size_t off = 0;
    auto alloc = [&](size_t bytes) -> char* {
        char* p = wsp + off;
        off += (bytes + 255) & ~(size_t)255;
        return p;
    };

    const size_t ipackHalf = (size_t)RBI * 16384;  // bytes per half (hi or lo)
    const size_t apackHalf = (size_t)RBA * 16384;

    unsigned short* invP_h = (unsigned short*)alloc(ipackHalf);
    unsigned short* invP_l = (unsigned short*)alloc(ipackHalf);
    unsigned short* astP_h = (unsigned short*)alloc(apackHalf);
    unsigned short* astP_l = (unsigned short*)alloc(apackHalf);
    // K_i f32; later overlaid by msgP_i (K_i dead after dir-2 attn)
    char* KfI_raw = alloc(2 * ipackHalf);
    float* KfI = (float*)KfI_raw;
    unsigned short* msgI_h = (unsigned short*)KfI_raw;
    unsigned short* msgI_l = (unsigned short*)(KfI_raw + ipackHalf);
    float* QfI = (float*)alloc((size_t)I * 1024);
    float* VfI = (float*)alloc((size_t)I * 1024);
    float* KfA = (float*)alloc((size_t)A * 1024);
    float* QfA = (float*)alloc((size_t)A * 1024);
    float* VfA = (float*)alloc((size_t)A * 1024);
    unsigned short* msgA_h = (unsigned short*)alloc(apackHalf);
    unsigned short* msgA_l = (unsigned short*)alloc(apackHalf);
    float* scbuf = (float*)alloc((size_t)E * 4 * 4);
    int* cnt_i  = (int*)alloc((size_t)I * 4);
    int* cnt_a  = (int*)alloc((size_t)A * 4);
    int* offs_i = (int*)alloc((size_t)(I + 1) * 4);
    int* offs_a = (int*)alloc((size_t)(A + 1) * 4);
    int* gsrc_i = (int*)alloc((size_t)E * 4);
    int* gsrc_a = (int*)alloc((size_t)E * 4);
    float* glw_i = (float*)alloc((size_t)E * 4);
    float* glw_a = (float*)alloc((size_t)E * 4);
    int* bsum_i = (int*)alloc(256 * 4);
    int* bsum_a = (int*)alloc(256 * 4);

    // weight packs: 0=m_w1 1=m_w2 2=Wq 3=Wk 4=Wv 5=u_w1 6=u_w2
    PrepArgs pa;
    const float* wsrc[7] = {m_w1, m_w2, Wq, Wk, Wv, u_w1, u_w2};
    const int    wK[7]   = {256, 256, 256, 256, 256, 512, 256};
    unsigned short* wph[7];
    unsigned short* wpl[7];
    pa.off[0] = 0;
    for (int i = 0; i < 7; ++i) {
        size_t slots = (size_t)(wK[i] >> 4) * 8 * 64;
        wph[i] = (unsigned short*)alloc(slots * 16);
        wpl[i] = (unsigned short*)alloc(slots * 16);
        pa.src[i] = wsrc[i];
        pa.hi[i] = wph[i];
        pa.lo[i] = wpl[i];
        pa.K[i] = wK[i];
        pa.off[i + 1] = pa.off[i] + (int)slots;
    }

    const int nbI = (I + 255) / 256;
    const int nbA = (A + 255) / 256;
    const int nbE = (E + 255) / 256;

    // ---- operand prep ----
    hipLaunchKernelGGL(prep_w, dim3((pa.off[7] + 255) / 256), dim3(256), 0, stream, pa);
    hipLaunchKernelGGL(pack_rows, dim3((RBI * 1024 + 255) / 256), dim3(256), 0, stream,
                       inv_h, invP_h, invP_l, I, RBI);
    hipLaunchKernelGGL(pack_rows, dim3((RBA * 1024 + 255) / 256), dim3(256), 0, stream,
                       asset_h, astP_h, astP_l, A, RBA);

    // ---- CSR build ----
    hipMemsetAsync(cnt_i, 0, (size_t)I * 4, stream);
    hipMemsetAsync(cnt_a, 0, (size_t)A * 4, stream);
    hipLaunchKernelGGL(count_kernel, dim3(nbE), dim3(256), 0, stream,
                       etgt, esrc, cnt_i, cnt_a, E);
    hipLaunchKernelGGL(scan_block, dim3(nbI), dim3(256), 0, stream, cnt_i, offs_i, bsum_i, I);
    hipLaunchKernelGGL(scan_block, dim3(nbA), dim3(256), 0, stream, cnt_a, offs_a, bsum_a, A);
    hipLaunchKernelGGL(scan_bsum, dim3(1), dim3(256), 0, stream, bsum_i, nbI);
    hipLaunchKernelGGL(scan_bsum, dim3(1), dim3(256), 0, stream, bsum_a, nbA);
    hipLaunchKernelGGL(add_offs, dim3(nbI), dim3(256), 0, stream, offs_i, cnt_i, bsum_i, I, E);
    hipLaunchKernelGGL(add_offs, dim3(nbA), dim3(256), 0, stream, offs_a, cnt_a, bsum_a, A, E);
    hipLaunchKernelGGL(fill_kernel, dim3(nbE), dim3(256), 0, stream,
                       etgt, esrc, inv_nw, asset_nw, cnt_i, cnt_a,
                       gsrc_i, glw_i, gsrc_a, glw_a, E);

    const unsigned LDSB = 32768 + 4 * 32 * 33 * 4;   // pack + per-wave tbuf = 49664

    // ---- phase 1: per node type, fused K/Q/t/M/V ----
    hipLaunchKernelGGL((fused_node<0>), dim3(RBI), dim3(256), LDSB, stream,
                       invP_h, invP_l, (const unsigned short*)nullptr, (const unsigned short*)nullptr,
                       wph[3], wpl[3],  // Wk
                       wph[2], wpl[2],  // Wq
                       wph[0], wpl[0],  // m_w1
                       wph[1], wpl[1],  // m_w2
                       wph[4], wpl[4],  // Wv
                       m_b1, m_b2, I, KfI, QfI, VfI);
    hipLaunchKernelGGL((fused_node<0>), dim3(RBA), dim3(256), LDSB, stream,
                       astP_h, astP_l, (const unsigned short*)nullptr, (const unsigned short*)nullptr,
                       wph[3], wpl[3], wph[2], wpl[2], wph[0], wpl[0],
                       wph[1], wpl[1], wph[4], wpl[4],
                       m_b1, m_b2, A, KfA, QfA, VfA);

    // ---- attention ----
    hipLaunchKernelGGL(fused_attn, dim3((A + 3) / 4), dim3(256), 0, stream,
                       QfA, KfI, VfI, offs_a, gsrc_a, glw_a, scbuf, msgA_h, msgA_l, A);
    hipLaunchKernelGGL(fused_attn, dim3((I + 3) / 4), dim3(256), 0, stream,
                       QfI, KfA, VfA, offs_i, gsrc_i, glw_i, scbuf, msgI_h, msgI_l, I);

    // ---- phase 2: fused hid->out ----
    hipLaunchKernelGGL((fused_node<1>), dim3(RBA), dim3(256), LDSB, stream,
                       astP_h, astP_l, msgA_h, msgA_l,
                       wph[5], wpl[5],  // u_w1
                       wph[6], wpl[6],  // u_w2
                       (const unsigned short*)nullptr, (const unsigned short*)nullptr,
                       (const unsigned short*)nullptr, (const unsigned short*)nullptr,
                       (const unsigned short*)nullptr, (const unsigned short*)nullptr,
                       u_b1, u_b2, A, (float*)nullptr, (float*)nullptr, out_asset);
    hipLaunchKernelGGL((fused_node<1>), dim3(RBI), dim3(256), LDSB, stream,
                       invP_h, invP_l, msgI_h, msgI_l,
                       wph[5], wpl[5], wph[6], wpl[6],
                       (const unsigned short*)nullptr, (const unsigned short*)nullptr,
                       (const unsigned short*)nullptr, (const unsigned short*)nullptr,
                       (const unsigned short*)nullptr, (const unsigned short*)nullptr,
                       u_b1, u_b2, I, (float*)nullptr, (float*)nullptr, out_inv);
}

// Round 8
// 880.274 us; speedup vs baseline: 1.0462x; 1.0462x over previous
//
#include <hip/hip_runtime.h>

typedef __bf16 bf16x8 __attribute__((ext_vector_type(8)));
typedef float f32x16 __attribute__((ext_vector_type(16)));
typedef unsigned short ushort8 __attribute__((ext_vector_type(8)));

// ---------- helpers ----------
__device__ __forceinline__ float gelu_exact(float x) {
    return 0.5f * x * (1.0f + erff(x * 0.70710678118654752440f));
}

// async global->LDS, 16B per lane; dest is wave-uniform base, HW adds lane*16
__device__ __forceinline__ void gload_lds16(const void* g, void* l) {
    __builtin_amdgcn_global_load_lds(
        (const __attribute__((address_space(1))) unsigned int*)g,
        (__attribute__((address_space(3))) unsigned int*)l, 16, 0, 0);
}

#define MFMA(a, b, c) __builtin_amdgcn_mfma_f32_32x32x16_bf16((a), (b), (c), 0, 0, 0)

// =====================================================================
// Packed operand layout (bf16 hi/lo, MFMA-fragment-linear):
//   A-pack for [M][256]: slot s = (rb*16 + kb)*64 + lane, 8 ushorts each.
//     lane's elems = A[rb*32 + (lane&31)][kb*16 + (lane>>5)*8 + i], i=0..7
//   B-pack for W[K][256]: slot = (nb*KB + kb)*64 + lane, KB = K/16.
//     lane's elems = W[kb*16 + (lane>>5)*8 + i][nb*32 + (lane&31)]
//   LDS A/pack region (32 rows x 256 k, hi/lo): byte(row,k) =
//     hl*16384 + (k>>4)*1024 + ((k>>3)&1)*512 + row*16 + (k&7)*2
//   LDS total 49664 B: pack 32768 + per-wave tbuf 4 x 32*33*4 (pad-33)
// =====================================================================

// ================= CSR build =================
__global__ __launch_bounds__(256) void count_kernel(
    const int* __restrict__ tgt, const int* __restrict__ src,
    int* __restrict__ cnt_i, int* __restrict__ cnt_a, int E)
{
    int e = blockIdx.x * 256 + threadIdx.x;
    if (e < E) {
        atomicAdd(&cnt_i[tgt[e]], 1);
        atomicAdd(&cnt_a[src[e]], 1);
    }
}

__global__ __launch_bounds__(256) void scan_block(
    const int* __restrict__ cnt, int* __restrict__ offs, int* __restrict__ bsum, int N)
{
    __shared__ int s[256];
    int i = blockIdx.x * 256 + threadIdx.x;
    int v = (i < N) ? cnt[i] : 0;
    s[threadIdx.x] = v;
    __syncthreads();
    for (int d = 1; d < 256; d <<= 1) {
        int t = (threadIdx.x >= d) ? s[threadIdx.x - d] : 0;
        __syncthreads();
        s[threadIdx.x] += t;
        __syncthreads();
    }
    if (i < N) offs[i] = s[threadIdx.x] - v;   // exclusive
    if (threadIdx.x == 255) bsum[blockIdx.x] = s[255];
}

__global__ __launch_bounds__(256) void scan_bsum(int* __restrict__ bsum, int nb)
{
    __shared__ int s[256];
    int v = (threadIdx.x < nb) ? bsum[threadIdx.x] : 0;
    s[threadIdx.x] = v;
    __syncthreads();
    for (int d = 1; d < 256; d <<= 1) {
        int t = (threadIdx.x >= d) ? s[threadIdx.x - d] : 0;
        __syncthreads();
        s[threadIdx.x] += t;
        __syncthreads();
    }
    if (threadIdx.x < nb) bsum[threadIdx.x] = s[threadIdx.x] - v;  // exclusive
}

__global__ __launch_bounds__(256) void add_offs(
    int* __restrict__ offs, int* __restrict__ cursor,
    const int* __restrict__ bsum, int N, int E)
{
    int i = blockIdx.x * 256 + threadIdx.x;
    if (i < N) {
        int f = offs[i] + bsum[blockIdx.x];
        offs[i] = f;
        cursor[i] = f;
    }
    if (i == 0) offs[N] = E;
}

// materialize CSR-ordered source index + log(nw)
__global__ __launch_bounds__(256) void fill_kernel(
    const int* __restrict__ tgt, const int* __restrict__ src,
    const float* __restrict__ nw_i, const float* __restrict__ nw_a,
    int* __restrict__ cur_i, int* __restrict__ cur_a,
    int* __restrict__ src_i, float* __restrict__ lw_i,
    int* __restrict__ src_a, float* __restrict__ lw_a, int E)
{
    int e = blockIdx.x * 256 + threadIdx.x;
    if (e < E) {
        int t = tgt[e], s = src[e];
        float li = logf(fmaxf(nw_i[e], 1e-10f));
        float la = logf(fmaxf(nw_a[e], 1e-10f));
        int p = atomicAdd(&cur_i[t], 1);
        src_i[p] = s; lw_i[p] = li;
        int q = atomicAdd(&cur_a[s], 1);
        src_a[q] = t; lw_a[q] = la;
    }
}

// ================= weight prep: f32 W[K][256] -> packed B fragments =================
struct PrepArgs {
    const float* src[7];
    unsigned short* hi[7];
    unsigned short* lo[7];
    int K[7];
    int off[8];   // slot offsets; slots per matrix = (K/16)*8*64
};

__global__ __launch_bounds__(256) void prep_w(PrepArgs a)
{
    int s = blockIdx.x * 256 + threadIdx.x;
    if (s >= a.off[7]) return;
    int m = 0;
    #pragma unroll
    for (int i = 0; i < 6; ++i) m += (s >= a.off[i + 1]) ? 1 : 0;
    int sl = s - a.off[m];
    int KB = a.K[m] >> 4;
    int l  = sl & 63;
    int kb = (sl >> 6) % KB;
    int nb = (sl >> 6) / KB;
    int n  = nb * 32 + (l & 31);
    int k0 = kb * 16 + ((l >> 5) << 3);
    ushort8 hh, ll;
    #pragma unroll
    for (int i = 0; i < 8; ++i) {
        float x = a.src[m][(size_t)(k0 + i) * 256 + n];
        __bf16 h = (__bf16)x;
        hh[i] = __builtin_bit_cast(unsigned short, h);
        ll[i] = __builtin_bit_cast(unsigned short, (__bf16)(x - (float)h));
    }
    *(ushort8*)(a.hi[m] + (size_t)sl * 8) = hh;
    *(ushort8*)(a.lo[m] + (size_t)sl * 8) = ll;
}

// ================= row pack: f32 X[M][256] -> packed A fragments =================
__global__ __launch_bounds__(256) void pack_rows(
    const float* __restrict__ X, unsigned short* __restrict__ Ph,
    unsigned short* __restrict__ Pl, int M, int RB)
{
    int s = blockIdx.x * 256 + threadIdx.x;
    int total = RB * 16 * 64;
    if (s >= total) return;
    int l  = s & 63;
    int kb = (s >> 6) & 15;
    int rb = s >> 10;
    int row = min(rb * 32 + (l & 31), M - 1);
    int k0  = kb * 16 + ((l >> 5) << 3);
    const float* p = X + (size_t)row * 256 + k0;
    float4 f0 = *(const float4*)p;
    float4 f1 = *(const float4*)(p + 4);
    float xs[8] = {f0.x, f0.y, f0.z, f0.w, f1.x, f1.y, f1.z, f1.w};
    ushort8 hh, ll;
    #pragma unroll
    for (int i = 0; i < 8; ++i) {
        __bf16 h = (__bf16)xs[i];
        hh[i] = __builtin_bit_cast(unsigned short, h);
        ll[i] = __builtin_bit_cast(unsigned short, (__bf16)(xs[i] - (float)h));
    }
    *(ushort8*)(Ph + (size_t)s * 8) = hh;
    *(ushort8*)(Pl + (size_t)s * 8) = ll;
}

// ================= fused per-target attention (unchanged, proven) =================
__global__ __launch_bounds__(256) void fused_attn(
    const float* __restrict__ Q, const float* __restrict__ Kk, const float* __restrict__ V,
    const int* __restrict__ offs, const int* __restrict__ srcs,
    const float* __restrict__ lws,
    float* __restrict__ scbuf, unsigned short* __restrict__ msgH,
    unsigned short* __restrict__ msgL, int T)
{
    int w = blockIdx.x * 4 + (threadIdx.x >> 6);
    int lane = threadIdx.x & 63;
    if (w >= T) return;
    int t = w;
    int beg = offs[t], end = offs[t + 1];
    int h = lane >> 4;

    float4 q = *(const float4*)(Q + (size_t)t * 256 + lane * 4);

    // ---- pass 1: scores + running max ----
    float mx = 0.f;   // 0-init matches torch scatter amax include_self with zeros
    {
        int sN = 0; float lC = 0.f, lN = 0.f;
        float4 k0 = make_float4(0.f, 0.f, 0.f, 0.f);
        if (beg < end) {
            int s0 = srcs[beg];
            lC = lws[beg];
            k0 = *(const float4*)(Kk + (size_t)s0 * 256 + lane * 4);
        }
        if (beg + 1 < end) { sN = srcs[beg + 1]; lN = lws[beg + 1]; }
        for (int j = beg; j < end; ++j) {
            int sNN = 0; float lNN = 0.f;
            if (j + 2 < end) { sNN = srcs[j + 2]; lNN = lws[j + 2]; }
            float4 k1 = k0;
            if (j + 1 < end) k1 = *(const float4*)(Kk + (size_t)sN * 256 + lane * 4);
            float d = q.x * k0.x + q.y * k0.y + q.z * k0.z + q.w * k0.w;
            d += __shfl_xor(d, 1);
            d += __shfl_xor(d, 2);
            d += __shfl_xor(d, 4);
            d += __shfl_xor(d, 8);
            float sc = d * 0.125f + lC;
            if ((lane & 15) == 0) scbuf[(size_t)j * 4 + h] = sc;
            mx = fmaxf(mx, sc);
            k0 = k1; lC = lN; sN = sNN; lN = lNN;
        }
    }

    // ---- pass 2: exp/sum + ex*V accumulate ----
    float sum = 0.f;
    float4 macc = make_float4(0.f, 0.f, 0.f, 0.f);
    {
        int sN = 0; float scC = 0.f, scN = 0.f;
        float4 v0 = make_float4(0.f, 0.f, 0.f, 0.f);
        if (beg < end) {
            int s0 = srcs[beg];
            scC = scbuf[(size_t)beg * 4 + h];
            v0 = *(const float4*)(V + (size_t)s0 * 256 + lane * 4);
        }
        if (beg + 1 < end) { sN = srcs[beg + 1]; scN = scbuf[(size_t)(beg + 1) * 4 + h]; }
        for (int j = beg; j < end; ++j) {
            int sNN = 0; float scNN = 0.f;
            if (j + 2 < end) { sNN = srcs[j + 2]; scNN = scbuf[(size_t)(j + 2) * 4 + h]; }
            float4 v1 = v0;
            if (j + 1 < end) v1 = *(const float4*)(V + (size_t)sN * 256 + lane * 4);
            float ex = expf(scC - mx);
            sum += ex;
            macc.x += ex * v0.x; macc.y += ex * v0.y;
            macc.z += ex * v0.z; macc.w += ex * v0.w;
            v0 = v1; scC = scN; sN = sNN; scN = scNN;
        }
    }
    float inv = 1.f / (sum + 1e-10f);
    float vals[4] = {macc.x * inv, macc.y * inv, macc.z * inv, macc.w * inv};
    unsigned short hs[4], ls[4];
    #pragma unroll
    for (int i = 0; i < 4; ++i) {
        __bf16 hh = (__bf16)vals[i];
        hs[i] = __builtin_bit_cast(unsigned short, hh);
        ls[i] = __builtin_bit_cast(unsigned short, (__bf16)(vals[i] - (float)hh));
    }
    // packed slot: cols c = 4*lane..4*lane+3 of row t
    size_t base = (((size_t)(t >> 5) * 16 + (lane >> 2)) * 64 + ((lane >> 1) & 1) * 32 + (t & 31)) * 8
                + ((lane & 1) << 2);
    *(ushort4*)(msgH + base) = make_ushort4(hs[0], hs[1], hs[2], hs[3]);
    *(ushort4*)(msgL + base) = make_ushort4(ls[0], ls[1], ls[2], ls[3]);
}

// ================= fused node kernel =================
// Block = 32 rows x 256 cols; 4 waves, wave w owns col-subtiles nb0=2w, 2w+1.
// MODE 0: stage 32-row h-pack slab ONCE into LDS, then 5 full-K loops off LDS:
//   K->HBM, Q->HBM, t->packed-in-LDS, M->packed-in-LDS, V->HBM.
// MODE 1: streamed counted-vmcnt pipeline over K=512 (concat h|msg) -> hid;
//   pack hid to LDS; out-loop reads pack, writes final output.
// B prefetch: depth-4 pipeline over NAMED ushort8 registers (no arrays, no
//   pointer-passing -> no scratch; rule #20 was round 7's regression).
// pack path: per-wave pad-33 f32 tbuf transpose -> ds_write_b128 pack (0 conflicts).
template<int MODE>
__global__ __launch_bounds__(256, 3) void fused_node(
    const unsigned short* __restrict__ Ah, const unsigned short* __restrict__ Al,
    const unsigned short* __restrict__ A2h, const unsigned short* __restrict__ A2l,
    const unsigned short* __restrict__ B1h, const unsigned short* __restrict__ B1l,  // Wk | u_w1
    const unsigned short* __restrict__ B2h, const unsigned short* __restrict__ B2l,  // Wq | u_w2
    const unsigned short* __restrict__ B3h, const unsigned short* __restrict__ B3l,  // m_w1
    const unsigned short* __restrict__ B4h, const unsigned short* __restrict__ B4l,  // m_w2
    const unsigned short* __restrict__ B5h, const unsigned short* __restrict__ B5l,  // Wv
    const float* __restrict__ bias1, const float* __restrict__ bias2,
    int M,
    float* __restrict__ O1, float* __restrict__ O2, float* __restrict__ O3)
{
    extern __shared__ char smem[];
    const int lane = threadIdx.x & 63;
    const int w = threadIdx.x >> 6;
    const int nb0 = w * 2;
    const int rb = blockIdx.x;
    float* tb = (float*)(smem + 32768 + w * 4224);   // per-wave 32 x 33 f32

    // full-K=256 GEMM off the LDS A/pack region; depth-4 named-register B pipeline.
    // B-pack offsets (ushorts): (nb*16 + kb)*512 + lane*8
    auto gemm_lds = [&](const unsigned short* BH, const unsigned short* BL,
                        f32x16& A0, f32x16& A1) {
        const unsigned short* p0h = BH + (size_t)nb0 * 8192 + lane * 8;
        const unsigned short* p0l = BL + (size_t)nb0 * 8192 + lane * 8;
        const unsigned short* p1h = p0h + 8192;
        const unsigned short* p1l = p0l + 8192;
        ushort8 r00, r01, r02, r03, r10, r11, r12, r13;
        ushort8 r20, r21, r22, r23, r30, r31, r32, r33;
#define LOADG(G, kb) do { \
        r##G##0 = *(const ushort8*)(p0h + (kb) * 512); \
        r##G##1 = *(const ushort8*)(p0l + (kb) * 512); \
        r##G##2 = *(const ushort8*)(p1h + (kb) * 512); \
        r##G##3 = *(const ushort8*)(p1l + (kb) * 512); \
    } while (0)
#define STEPG(G, kb, kbn, DO) do { \
        bf16x8 ah  = __builtin_bit_cast(bf16x8, *(const ushort8*)(smem + (kb) * 1024 + lane * 16)); \
        bf16x8 alo = __builtin_bit_cast(bf16x8, *(const ushort8*)(smem + 16384 + (kb) * 1024 + lane * 16)); \
        bf16x8 b0h = __builtin_bit_cast(bf16x8, r##G##0); \
        bf16x8 b0l = __builtin_bit_cast(bf16x8, r##G##1); \
        bf16x8 c1h = __builtin_bit_cast(bf16x8, r##G##2); \
        bf16x8 c1l = __builtin_bit_cast(bf16x8, r##G##3); \
        A0 = MFMA(ah, b0h, A0); A0 = MFMA(ah, b0l, A0); A0 = MFMA(alo, b0h, A0); \
        A1 = MFMA(ah, c1h, A1); A1 = MFMA(ah, c1l, A1); A1 = MFMA(alo, c1h, A1); \
        if (DO) LOADG(G, kbn); \
    } while (0)
        LOADG(0, 0); LOADG(1, 1); LOADG(2, 2); LOADG(3, 3);
        STEPG(0, 0, 4, 1);  STEPG(1, 1, 5, 1);  STEPG(2, 2, 6, 1);  STEPG(3, 3, 7, 1);
        STEPG(0, 4, 8, 1);  STEPG(1, 5, 9, 1);  STEPG(2, 6, 10, 1); STEPG(3, 7, 11, 1);
        STEPG(0, 8, 12, 1); STEPG(1, 9, 13, 1); STEPG(2, 10, 14, 1);STEPG(3, 11, 15, 1);
        STEPG(0, 12, 0, 0); STEPG(1, 13, 0, 0); STEPG(2, 14, 0, 0); STEPG(3, 15, 0, 0);
#undef LOADG
#undef STEPG
    };

    // C/D layout: col = lane&31, row = (r&3) + 8*(r>>2) + 4*(lane>>5)
    auto store_f32 = [&](const f32x16& A0, const f32x16& A1, const float* bias, int act,
                         float* Out) {
        #pragma unroll
        for (int nt = 0; nt < 2; ++nt) {
            const f32x16& a = nt ? A1 : A0;
            int n = (nb0 + nt) * 32 + (lane & 31);
            float bv = bias ? bias[n] : 0.f;
            #pragma unroll
            for (int r = 0; r < 16; ++r) {
                int row = rb * 32 + (r & 3) + ((r >> 2) << 3) + ((lane >> 5) << 2);
                if (row < M) {
                    float v = a[r] + bv;
                    if (act) v = gelu_exact(v);
                    Out[(size_t)row * 256 + n] = v;
                }
            }
        }
    };

    // bias + GELU + hi/lo split into pack region, via per-wave pad-33 tbuf transpose
    auto pack_to_lds = [&](const f32x16& A0, const f32x16& A1, const float* bias) {
        #pragma unroll
        for (int nt = 0; nt < 2; ++nt) {
            const f32x16& a = nt ? A1 : A0;
            int nloc = lane & 31;
            float bv = bias[(nb0 + nt) * 32 + nloc];
            #pragma unroll
            for (int r = 0; r < 16; ++r) {
                int m = (r & 3) + ((r >> 2) << 3) + ((lane >> 5) << 2);
                tb[m * 33 + nloc] = gelu_exact(a[r] + bv);
            }
            asm volatile("s_waitcnt lgkmcnt(0)" ::: "memory");
            #pragma unroll
            for (int qq = 0; qq < 2; ++qq) {
                int c0 = ((lane >> 5) << 3) + (qq << 4);   // local col block 0,8,16,24
                int m2 = lane & 31;
                float vs[8];
                #pragma unroll
                for (int i = 0; i < 8; ++i) vs[i] = tb[m2 * 33 + c0 + i];
                ushort8 hh, ll;
                #pragma unroll
                for (int i = 0; i < 8; ++i) {
                    __bf16 hb = (__bf16)vs[i];
                    hh[i] = __builtin_bit_cast(unsigned short, hb);
                    ll[i] = __builtin_bit_cast(unsigned short, (__bf16)(vs[i] - (float)hb));
                }
                int ng = (nb0 + nt) * 32 + c0;   // global col of first elem
                char* dsth = smem + (ng >> 4) * 1024 + ((ng >> 3) & 1) * 512 + m2 * 16;
                *(ushort8*)dsth = hh;
                *(ushort8*)(dsth + 16384) = ll;
            }
            asm volatile("s_waitcnt lgkmcnt(0)" ::: "memory");  // tb reuse (same wave)
        }
    };

    if constexpr (MODE == 0) {
        // ---- one-shot stage of the 32-row h slab (32 KB) ----
        #pragma unroll
        for (int i = 0; i < 8; ++i) {
            int u = w * 8 + i, hl = u >> 4, kb = u & 15;
            const unsigned short* srcp = hl ? Al : Ah;
            const unsigned short* g = srcp + ((size_t)(rb * 16 + kb) * 64 + lane) * 8;
            gload_lds16(g, smem + hl * 16384 + kb * 1024);
        }
        asm volatile("s_waitcnt vmcnt(0)" ::: "memory");
        __builtin_amdgcn_s_barrier();

        { f32x16 a0 = {}, a1 = {}; gemm_lds(B1h, B1l, a0, a1);
          store_f32(a0, a1, nullptr, 0, O1); }                    // K = h@Wk
        { f32x16 a0 = {}, a1 = {}; gemm_lds(B2h, B2l, a0, a1);
          store_f32(a0, a1, nullptr, 0, O2); }                    // Q = h@Wq
        f32x16 t0 = {}, t1 = {};
        gemm_lds(B3h, B3l, t0, t1);                               // t = h@m_w1
        __syncthreads();                                          // all A reads done
        pack_to_lds(t0, t1, bias1);                               // gelu(t+b1) -> LDS
        __syncthreads();
        f32x16 m0 = {}, m1 = {};
        gemm_lds(B4h, B4l, m0, m1);                               // M = t@m_w2
        __syncthreads();
        pack_to_lds(m0, m1, bias2);                               // gelu(M+b2) -> LDS
        __syncthreads();
        { f32x16 a0 = {}, a1 = {}; gemm_lds(B5h, B5l, a0, a1);
          store_f32(a0, a1, nullptr, 0, O3); }                    // V = M@Wv
    } else {
        // ---- phase 2: streamed hid over K=512 (counted-vmcnt, 3-buffer) ----
        auto stage_one = [&](int bufn, int st, int u) {
            int hl = u >> 2, kb = u & 3;
            int kbg = st * 4 + kb;
            const unsigned short* srcp; int kba = kbg;
            if (kbg >= 16) { kba = kbg - 16; srcp = hl ? A2l : A2h; }
            else           { srcp = hl ? Al : Ah; }
            const unsigned short* g = srcp + ((size_t)(rb * 16 + kba) * 64 + lane) * 8;
            gload_lds16(g, smem + bufn * 8192 + (hl * 4 + kb) * 1024);
        };
        stage_one(0, 0, w * 2); stage_one(0, 0, w * 2 + 1);
        stage_one(1, 1, w * 2); stage_one(1, 1, w * 2 + 1);
        asm volatile("s_waitcnt vmcnt(2)" ::: "memory");
        __builtin_amdgcn_s_barrier();

        // u_w1 pack base (KB=32): (nb*32 + kbg)*512 + lane*8 ushorts
        const unsigned short* u0h = B1h + (size_t)nb0 * 16384 + lane * 8;
        const unsigned short* u0l = B1l + (size_t)nb0 * 16384 + lane * 8;
        const unsigned short* u1h = u0h + 16384;
        const unsigned short* u1l = u0l + 16384;

        f32x16 h0 = {}, h1 = {};
        for (int st = 0; st < 8; ++st) {
            if (st) {
                // per iter: 16 B-loads + 2 staging = 18 newer than stage st's loads
                asm volatile("s_waitcnt vmcnt(18)" ::: "memory");
                __builtin_amdgcn_s_barrier();
            }
            const int buf = st % 3;
            const int kg0 = st * 4;
            ushort8 q00, q01, q02, q03, q10, q11, q12, q13;
            ushort8 q20, q21, q22, q23, q30, q31, q32, q33;
#define LOADQ(G, kb) do { \
            q##G##0 = *(const ushort8*)(u0h + (size_t)(kg0 + (kb)) * 512); \
            q##G##1 = *(const ushort8*)(u0l + (size_t)(kg0 + (kb)) * 512); \
            q##G##2 = *(const ushort8*)(u1h + (size_t)(kg0 + (kb)) * 512); \
            q##G##3 = *(const ushort8*)(u1l + (size_t)(kg0 + (kb)) * 512); \
    } while (0)
            LOADQ(0, 0); LOADQ(1, 1); LOADQ(2, 2); LOADQ(3, 3);
            {
                int bufn = (st + 2) % 3;
                int stc = (st + 2 < 8) ? (st + 2) : 7;   // tail: harmless reload
                stage_one(bufn, stc, w * 2);
                stage_one(bufn, stc, w * 2 + 1);
            }
#define STEPQ(G, kb) do { \
            bf16x8 ah  = __builtin_bit_cast(bf16x8, \
                *(const ushort8*)(smem + buf * 8192 + (kb) * 1024 + lane * 16)); \
            bf16x8 alo = __builtin_bit_cast(bf16x8, \
                *(const ushort8*)(smem + buf * 8192 + (4 + (kb)) * 1024 + lane * 16)); \
            bf16x8 b0h = __builtin_bit_cast(bf16x8, q##G##0); \
            bf16x8 b0l = __builtin_bit_cast(bf16x8, q##G##1); \
            bf16x8 c1h = __builtin_bit_cast(bf16x8, q##G##2); \
            bf16x8 c1l = __builtin_bit_cast(bf16x8, q##G##3); \
            h0 = MFMA(ah, b0h, h0); h0 = MFMA(ah, b0l, h0); h0 = MFMA(alo, b0h, h0); \
            h1 = MFMA(ah, c1h, h1); h1 = MFMA(ah, c1l, h1); h1 = MFMA(alo, c1h, h1); \
    } while (0)
            STEPQ(0, 0); STEPQ(1, 1); STEPQ(2, 2); STEPQ(3, 3);
#undef LOADQ
#undef STEPQ
        }
        asm volatile("s_waitcnt vmcnt(0)" ::: "memory");   // drain stray prefetches
        __builtin_amdgcn_s_barrier();

        pack_to_lds(h0, h1, bias1);                        // gelu(hid+u_b1) -> LDS
        __syncthreads();
        { f32x16 o0 = {}, o1 = {}; gemm_lds(B2h, B2l, o0, o1);
          store_f32(o0, o1, bias2, 1, O3); }               // out = gelu(hid@u_w2+u_b2)
    }
}

// ================= host =================
extern "C" void kernel_launch(void* const* d_in, const int* in_sizes, int n_in,
                              void* d_out, int out_size, void* d_ws, size_t ws_size,
                              hipStream_t stream) {
    const float* inv_h    = (const float*)d_in[0];
    const float* asset_h  = (const float*)d_in[1];
    const float* inv_nw   = (const float*)d_in[2];
    const float* asset_nw = (const float*)d_in[3];
    const float* m_w1 = (const float*)d_in[4];
    const float* m_b1 = (const float*)d_in[5];
    const float* m_w2 = (const float*)d_in[6];
    const float* m_b2 = (const float*)d_in[7];
    const float* Wq   = (const float*)d_in[8];
    const float* Wk   = (const float*)d_in[9];
    const float* Wv   = (const float*)d_in[10];
    const float* u_w1 = (const float*)d_in[11];
    const float* u_b1 = (const float*)d_in[12];
    const float* u_w2 = (const float*)d_in[13];
    const float* u_b2 = (const float*)d_in[14];
    const int* etgt  = (const int*)d_in[15];
    const int* esrc  = (const int*)d_in[16];

    const int I = in_sizes[0] / 256;
    const int A = in_sizes[1] / 256;
    const int E = in_sizes[15];
    const int RBI = (I + 31) >> 5;
    const int RBA = (A + 31) >> 5;

    float* out_inv   = (float*)d_out;
    float* out_asset = (float*)d_out + (size_t)I * 256;

    char* wsp = (char*)d_ws;
    size_t off = 0;
    auto alloc = [&](size_t bytes) -> char* {
        char* p = wsp + off;
        off += (bytes + 255) & ~(size_t)255;
        return p;
    };

    const size_t ipackHalf = (size_t)RBI * 16384;  // bytes per half (hi or lo)
    const size_t apackHalf = (size_t)RBA * 16384;

    unsigned short* invP_h = (unsigned short*)alloc(ipackHalf);
    unsigned short* invP_l = (unsigned short*)alloc(ipackHalf);
    unsigned short* astP_h = (unsigned short*)alloc(apackHalf);
    unsigned short* astP_l = (unsigned short*)alloc(apackHalf);
    // K_i f32; later overlaid by msgP_i (K_i dead after dir-2 attn)
    char* KfI_raw = alloc(2 * ipackHalf);
    float* KfI = (float*)KfI_raw;
    unsigned short* msgI_h = (unsigned short*)KfI_raw;
    unsigned short* msgI_l = (unsigned short*)(KfI_raw + ipackHalf);
    float* QfI = (float*)alloc((size_t)I * 1024);
    float* VfI = (float*)alloc((size_t)I * 1024);
    float* KfA = (float*)alloc((size_t)A * 1024);
    float* QfA = (float*)alloc((size_t)A * 1024);
    float* VfA = (float*)alloc((size_t)A * 1024);
    unsigned short* msgA_h = (unsigned short*)alloc(apackHalf);
    unsigned short* msgA_l = (unsigned short*)alloc(apackHalf);
    float* scbuf = (float*)alloc((size_t)E * 4 * 4);
    int* cnt_i  = (int*)alloc((size_t)I * 4);
    int* cnt_a  = (int*)alloc((size_t)A * 4);
    int* offs_i = (int*)alloc((size_t)(I + 1) * 4);
    int* offs_a = (int*)alloc((size_t)(A + 1) * 4);
    int* gsrc_i = (int*)alloc((size_t)E * 4);
    int* gsrc_a = (int*)alloc((size_t)E * 4);
    float* glw_i = (float*)alloc((size_t)E * 4);
    float* glw_a = (float*)alloc((size_t)E * 4);
    int* bsum_i = (int*)alloc(256 * 4);
    int* bsum_a = (int*)alloc(256 * 4);

    // weight packs: 0=m_w1 1=m_w2 2=Wq 3=Wk 4=Wv 5=u_w1 6=u_w2
    PrepArgs pa;
    const float* wsrc[7] = {m_w1, m_w2, Wq, Wk, Wv, u_w1, u_w2};
    const int    wK[7]   = {256, 256, 256, 256, 256, 512, 256};
    unsigned short* wph[7];
    unsigned short* wpl[7];
    pa.off[0] = 0;
    for (int i = 0; i < 7; ++i) {
        size_t slots = (size_t)(wK[i] >> 4) * 8 * 64;
        wph[i] = (unsigned short*)alloc(slots * 16);
        wpl[i] = (unsigned short*)alloc(slots * 16);
        pa.src[i] = wsrc[i];
        pa.hi[i] = wph[i];
        pa.lo[i] = wpl[i];
        pa.K[i] = wK[i];
        pa.off[i + 1] = pa.off[i] + (int)slots;
    }

    const int nbI = (I + 255) / 256;
    const int nbA = (A + 255) / 256;
    const int nbE = (E + 255) / 256;

    // ---- operand prep ----
    hipLaunchKernelGGL(prep_w, dim3((pa.off[7] + 255) / 256), dim3(256), 0, stream, pa);
    hipLaunchKernelGGL(pack_rows, dim3((RBI * 1024 + 255) / 256), dim3(256), 0, stream,
                       inv_h, invP_h, invP_l, I, RBI);
    hipLaunchKernelGGL(pack_rows, dim3((RBA * 1024 + 255) / 256), dim3(256), 0, stream,
                       asset_h, astP_h, astP_l, A, RBA);

    // ---- CSR build ----
    hipMemsetAsync(cnt_i, 0, (size_t)I * 4, stream);
    hipMemsetAsync(cnt_a, 0, (size_t)A * 4, stream);
    hipLaunchKernelGGL(count_kernel, dim3(nbE), dim3(256), 0, stream,
                       etgt, esrc, cnt_i, cnt_a, E);
    hipLaunchKernelGGL(scan_block, dim3(nbI), dim3(256), 0, stream, cnt_i, offs_i, bsum_i, I);
    hipLaunchKernelGGL(scan_block, dim3(nbA), dim3(256), 0, stream, cnt_a, offs_a, bsum_a, A);
    hipLaunchKernelGGL(scan_bsum, dim3(1), dim3(256), 0, stream, bsum_i, nbI);
    hipLaunchKernelGGL(scan_bsum, dim3(1), dim3(256), 0, stream, bsum_a, nbA);
    hipLaunchKernelGGL(add_offs, dim3(nbI), dim3(256), 0, stream, offs_i, cnt_i, bsum_i, I, E);
    hipLaunchKernelGGL(add_offs, dim3(nbA), dim3(256), 0, stream, offs_a, cnt_a, bsum_a, A, E);
    hipLaunchKernelGGL(fill_kernel, dim3(nbE), dim3(256), 0, stream,
                       etgt, esrc, inv_nw, asset_nw, cnt_i, cnt_a,
                       gsrc_i, glw_i, gsrc_a, glw_a, E);

    const unsigned LDSB = 32768 + 4 * 32 * 33 * 4;   // pack + per-wave tbuf = 49664

    // ---- phase 1: per node type, fused K/Q/t/M/V ----
    hipLaunchKernelGGL((fused_node<0>), dim3(RBI), dim3(256), LDSB, stream,
                       invP_h, invP_l, (const unsigned short*)nullptr, (const unsigned short*)nullptr,
                       wph[3], wpl[3],  // Wk
                       wph[2], wpl[2],  // Wq
                       wph[0], wpl[0],  // m_w1
                       wph[1], wpl[1],  // m_w2
                       wph[4], wpl[4],  // Wv
                       m_b1, m_b2, I, KfI, QfI, VfI);
    hipLaunchKernelGGL((fused_node<0>), dim3(RBA), dim3(256), LDSB, stream,
                       astP_h, astP_l, (const unsigned short*)nullptr, (const unsigned short*)nullptr,
                       wph[3], wpl[3], wph[2], wpl[2], wph[0], wpl[0],
                       wph[1], wpl[1], wph[4], wpl[4],
                       m_b1, m_b2, A, KfA, QfA, VfA);

    // ---- attention ----
    hipLaunchKernelGGL(fused_attn, dim3((A + 3) / 4), dim3(256), 0, stream,
                       QfA, KfI, VfI, offs_a, gsrc_a, glw_a, scbuf, msgA_h, msgA_l, A);
    hipLaunchKernelGGL(fused_attn, dim3((I + 3) / 4), dim3(256), 0, stream,
                       QfI, KfA, VfA, offs_i, gsrc_i, glw_i, scbuf, msgI_h, msgI_l, I);

    // ---- phase 2: fused hid->out ----
    hipLaunchKernelGGL((fused_node<1>), dim3(RBA), dim3(256), LDSB, stream,
                       astP_h, astP_l, msgA_h, msgA_l,
                       wph[5], wpl[5],  // u_w1
                       wph[6], wpl[6],  // u_w2
                       (const unsigned short*)nullptr, (const unsigned short*)nullptr,
                       (const unsigned short*)nullptr, (const unsigned short*)nullptr,
                       (const unsigned short*)nullptr, (const unsigned short*)nullptr,
                       u_b1, u_b2, A, (float*)nullptr, (float*)nullptr, out_asset);
    hipLaunchKernelGGL((fused_node<1>), dim3(RBI), dim3(256), LDSB, stream,
                       invP_h, invP_l, msgI_h, msgI_l,
                       wph[5], wpl[5], wph[6], wpl[6],
                       (const unsigned short*)nullptr, (const unsigned short*)nullptr,
                       (const unsigned short*)nullptr, (const unsigned short*)nullptr,
                       (const unsigned short*)nullptr, (const unsigned short*)nullptr,
                       u_b1, u_b2, I, (float*)nullptr, (float*)nullptr, out_inv);
}

// Round 9
// 758.688 us; speedup vs baseline: 1.2139x; 1.1603x over previous
//
#include <hip/hip_runtime.h>

typedef __bf16 bf16x8 __attribute__((ext_vector_type(8)));
typedef float f32x16 __attribute__((ext_vector_type(16)));
typedef unsigned short ushort8 __attribute__((ext_vector_type(8)));

// ---------- helpers ----------
__device__ __forceinline__ float gelu_exact(float x) {
    return 0.5f * x * (1.0f + erff(x * 0.70710678118654752440f));
}

// async global->LDS, 16B per lane; dest is wave-uniform base, HW adds lane*16
__device__ __forceinline__ void gload_lds16(const void* g, void* l) {
    __builtin_amdgcn_global_load_lds(
        (const __attribute__((address_space(1))) unsigned int*)g,
        (__attribute__((address_space(3))) unsigned int*)l, 16, 0, 0);
}

#define MFMA(a, b, c) __builtin_amdgcn_mfma_f32_32x32x16_bf16((a), (b), (c), 0, 0, 0)

// =====================================================================
// Packed operand layout (bf16 hi/lo, MFMA-fragment-linear):
//   A-pack for [M][256]: slot s = (rb*16 + kb)*64 + lane, 8 ushorts each.
//     lane's elems = A[rb*32 + (lane&31)][kb*16 + (lane>>5)*8 + i], i=0..7
//   B-pack for W[K][256]: slot = (nb*KB + kb)*64 + lane, KB = K/16.
//     lane's elems = W[kb*16 + (lane>>5)*8 + i][nb*32 + (lane&31)]
//   LDS A/pack region (32 rows x 256 k, hi/lo): byte(row,k) =
//     hl*16384 + (k>>4)*1024 + ((k>>3)&1)*512 + row*16 + (k&7)*2
//   LDS total 49664 B: pack 32768 + per-wave tbuf 4 x 32*33*4 (pad-33)
// =====================================================================

// ================= CSR build =================
__global__ __launch_bounds__(256) void count_kernel(
    const int* __restrict__ tgt, const int* __restrict__ src,
    int* __restrict__ cnt_i, int* __restrict__ cnt_a, int E)
{
    int e = blockIdx.x * 256 + threadIdx.x;
    if (e < E) {
        atomicAdd(&cnt_i[tgt[e]], 1);
        atomicAdd(&cnt_a[src[e]], 1);
    }
}

__global__ __launch_bounds__(256) void scan_block(
    const int* __restrict__ cnt, int* __restrict__ offs, int* __restrict__ bsum, int N)
{
    __shared__ int s[256];
    int i = blockIdx.x * 256 + threadIdx.x;
    int v = (i < N) ? cnt[i] : 0;
    s[threadIdx.x] = v;
    __syncthreads();
    for (int d = 1; d < 256; d <<= 1) {
        int t = (threadIdx.x >= d) ? s[threadIdx.x - d] : 0;
        __syncthreads();
        s[threadIdx.x] += t;
        __syncthreads();
    }
    if (i < N) offs[i] = s[threadIdx.x] - v;   // exclusive
    if (threadIdx.x == 255) bsum[blockIdx.x] = s[255];
}

__global__ __launch_bounds__(256) void scan_bsum(int* __restrict__ bsum, int nb)
{
    __shared__ int s[256];
    int v = (threadIdx.x < nb) ? bsum[threadIdx.x] : 0;
    s[threadIdx.x] = v;
    __syncthreads();
    for (int d = 1; d < 256; d <<= 1) {
        int t = (threadIdx.x >= d) ? s[threadIdx.x - d] : 0;
        __syncthreads();
        s[threadIdx.x] += t;
        __syncthreads();
    }
    if (threadIdx.x < nb) bsum[threadIdx.x] = s[threadIdx.x] - v;  // exclusive
}

__global__ __launch_bounds__(256) void add_offs(
    int* __restrict__ offs, int* __restrict__ cursor,
    const int* __restrict__ bsum, int N, int E)
{
    int i = blockIdx.x * 256 + threadIdx.x;
    if (i < N) {
        int f = offs[i] + bsum[blockIdx.x];
        offs[i] = f;
        cursor[i] = f;
    }
    if (i == 0) offs[N] = E;
}

// materialize CSR-ordered source index + log(nw)
__global__ __launch_bounds__(256) void fill_kernel(
    const int* __restrict__ tgt, const int* __restrict__ src,
    const float* __restrict__ nw_i, const float* __restrict__ nw_a,
    int* __restrict__ cur_i, int* __restrict__ cur_a,
    int* __restrict__ src_i, float* __restrict__ lw_i,
    int* __restrict__ src_a, float* __restrict__ lw_a, int E)
{
    int e = blockIdx.x * 256 + threadIdx.x;
    if (e < E) {
        int t = tgt[e], s = src[e];
        float li = logf(fmaxf(nw_i[e], 1e-10f));
        float la = logf(fmaxf(nw_a[e], 1e-10f));
        int p = atomicAdd(&cur_i[t], 1);
        src_i[p] = s; lw_i[p] = li;
        int q = atomicAdd(&cur_a[s], 1);
        src_a[q] = t; lw_a[q] = la;
    }
}

// ================= weight prep: f32 W[K][256] -> packed B fragments =================
struct PrepArgs {
    const float* src[7];
    unsigned short* hi[7];
    unsigned short* lo[7];
    int K[7];
    int off[8];   // slot offsets; slots per matrix = (K/16)*8*64
};

__global__ __launch_bounds__(256) void prep_w(PrepArgs a)
{
    int s = blockIdx.x * 256 + threadIdx.x;
    if (s >= a.off[7]) return;
    int m = 0;
    #pragma unroll
    for (int i = 0; i < 6; ++i) m += (s >= a.off[i + 1]) ? 1 : 0;
    int sl = s - a.off[m];
    int KB = a.K[m] >> 4;
    int l  = sl & 63;
    int kb = (sl >> 6) % KB;
    int nb = (sl >> 6) / KB;
    int n  = nb * 32 + (l & 31);
    int k0 = kb * 16 + ((l >> 5) << 3);
    ushort8 hh, ll;
    #pragma unroll
    for (int i = 0; i < 8; ++i) {
        float x = a.src[m][(size_t)(k0 + i) * 256 + n];
        __bf16 h = (__bf16)x;
        hh[i] = __builtin_bit_cast(unsigned short, h);
        ll[i] = __builtin_bit_cast(unsigned short, (__bf16)(x - (float)h));
    }
    *(ushort8*)(a.hi[m] + (size_t)sl * 8) = hh;
    *(ushort8*)(a.lo[m] + (size_t)sl * 8) = ll;
}

// ================= row pack: f32 X[M][256] -> packed A fragments =================
__global__ __launch_bounds__(256) void pack_rows(
    const float* __restrict__ X, unsigned short* __restrict__ Ph,
    unsigned short* __restrict__ Pl, int M, int RB)
{
    int s = blockIdx.x * 256 + threadIdx.x;
    int total = RB * 16 * 64;
    if (s >= total) return;
    int l  = s & 63;
    int kb = (s >> 6) & 15;
    int rb = s >> 10;
    int row = min(rb * 32 + (l & 31), M - 1);
    int k0  = kb * 16 + ((l >> 5) << 3);
    const float* p = X + (size_t)row * 256 + k0;
    float4 f0 = *(const float4*)p;
    float4 f1 = *(const float4*)(p + 4);
    float xs[8] = {f0.x, f0.y, f0.z, f0.w, f1.x, f1.y, f1.z, f1.w};
    ushort8 hh, ll;
    #pragma unroll
    for (int i = 0; i < 8; ++i) {
        __bf16 h = (__bf16)xs[i];
        hh[i] = __builtin_bit_cast(unsigned short, h);
        ll[i] = __builtin_bit_cast(unsigned short, (__bf16)(xs[i] - (float)h));
    }
    *(ushort8*)(Ph + (size_t)s * 8) = hh;
    *(ushort8*)(Pl + (size_t)s * 8) = ll;
}

// ================= fused per-target attention (unchanged, proven) =================
__global__ __launch_bounds__(256) void fused_attn(
    const float* __restrict__ Q, const float* __restrict__ Kk, const float* __restrict__ V,
    const int* __restrict__ offs, const int* __restrict__ srcs,
    const float* __restrict__ lws,
    float* __restrict__ scbuf, unsigned short* __restrict__ msgH,
    unsigned short* __restrict__ msgL, int T)
{
    int w = blockIdx.x * 4 + (threadIdx.x >> 6);
    int lane = threadIdx.x & 63;
    if (w >= T) return;
    int t = w;
    int beg = offs[t], end = offs[t + 1];
    int h = lane >> 4;

    float4 q = *(const float4*)(Q + (size_t)t * 256 + lane * 4);

    // ---- pass 1: scores + running max ----
    float mx = 0.f;   // 0-init matches torch scatter amax include_self with zeros
    {
        int sN = 0; float lC = 0.f, lN = 0.f;
        float4 k0 = make_float4(0.f, 0.f, 0.f, 0.f);
        if (beg < end) {
            int s0 = srcs[beg];
            lC = lws[beg];
            k0 = *(const float4*)(Kk + (size_t)s0 * 256 + lane * 4);
        }
        if (beg + 1 < end) { sN = srcs[beg + 1]; lN = lws[beg + 1]; }
        for (int j = beg; j < end; ++j) {
            int sNN = 0; float lNN = 0.f;
            if (j + 2 < end) { sNN = srcs[j + 2]; lNN = lws[j + 2]; }
            float4 k1 = k0;
            if (j + 1 < end) k1 = *(const float4*)(Kk + (size_t)sN * 256 + lane * 4);
            float d = q.x * k0.x + q.y * k0.y + q.z * k0.z + q.w * k0.w;
            d += __shfl_xor(d, 1);
            d += __shfl_xor(d, 2);
            d += __shfl_xor(d, 4);
            d += __shfl_xor(d, 8);
            float sc = d * 0.125f + lC;
            if ((lane & 15) == 0) scbuf[(size_t)j * 4 + h] = sc;
            mx = fmaxf(mx, sc);
            k0 = k1; lC = lN; sN = sNN; lN = lNN;
        }
    }

    // ---- pass 2: exp/sum + ex*V accumulate ----
    float sum = 0.f;
    float4 macc = make_float4(0.f, 0.f, 0.f, 0.f);
    {
        int sN = 0; float scC = 0.f, scN = 0.f;
        float4 v0 = make_float4(0.f, 0.f, 0.f, 0.f);
        if (beg < end) {
            int s0 = srcs[beg];
            scC = scbuf[(size_t)beg * 4 + h];
            v0 = *(const float4*)(V + (size_t)s0 * 256 + lane * 4);
        }
        if (beg + 1 < end) { sN = srcs[beg + 1]; scN = scbuf[(size_t)(beg + 1) * 4 + h]; }
        for (int j = beg; j < end; ++j) {
            int sNN = 0; float scNN = 0.f;
            if (j + 2 < end) { sNN = srcs[j + 2]; scNN = scbuf[(size_t)(j + 2) * 4 + h]; }
            float4 v1 = v0;
            if (j + 1 < end) v1 = *(const float4*)(V + (size_t)sN * 256 + lane * 4);
            float ex = expf(scC - mx);
            sum += ex;
            macc.x += ex * v0.x; macc.y += ex * v0.y;
            macc.z += ex * v0.z; macc.w += ex * v0.w;
            v0 = v1; scC = scN; sN = sNN; scN = scNN;
        }
    }
    float inv = 1.f / (sum + 1e-10f);
    float vals[4] = {macc.x * inv, macc.y * inv, macc.z * inv, macc.w * inv};
    unsigned short hs[4], ls[4];
    #pragma unroll
    for (int i = 0; i < 4; ++i) {
        __bf16 hh = (__bf16)vals[i];
        hs[i] = __builtin_bit_cast(unsigned short, hh);
        ls[i] = __builtin_bit_cast(unsigned short, (__bf16)(vals[i] - (float)hh));
    }
    // packed slot: cols c = 4*lane..4*lane+3 of row t
    size_t base = (((size_t)(t >> 5) * 16 + (lane >> 2)) * 64 + ((lane >> 1) & 1) * 32 + (t & 31)) * 8
                + ((lane & 1) << 2);
    *(ushort4*)(msgH + base) = make_ushort4(hs[0], hs[1], hs[2], hs[3]);
    *(ushort4*)(msgL + base) = make_ushort4(ls[0], ls[1], ls[2], ls[3]);
}

// ================= forceinline GEMM helpers (round-8 lesson: the big lambda
// was NOT inlined -> acc passed by reference through scratch; __forceinline__
// free functions make inlining mandatory) =================

// full-K=256 GEMM off the LDS A/pack region; depth-4 named-register B pipeline.
// B-pack offsets (ushorts): (nb*16 + kb)*512 + lane*8
__device__ __forceinline__ void gemm_lds256(
    char* __restrict__ smem, const int lane, const int nb0,
    const unsigned short* __restrict__ BH, const unsigned short* __restrict__ BL,
    f32x16& A0, f32x16& A1)
{
    const unsigned short* p0h = BH + (size_t)nb0 * 8192 + lane * 8;
    const unsigned short* p0l = BL + (size_t)nb0 * 8192 + lane * 8;
    const unsigned short* p1h = p0h + 8192;
    const unsigned short* p1l = p0l + 8192;
    ushort8 r00, r01, r02, r03, r10, r11, r12, r13;
    ushort8 r20, r21, r22, r23, r30, r31, r32, r33;
#define LOADG(G, kb) do { \
        r##G##0 = *(const ushort8*)(p0h + (kb) * 512); \
        r##G##1 = *(const ushort8*)(p0l + (kb) * 512); \
        r##G##2 = *(const ushort8*)(p1h + (kb) * 512); \
        r##G##3 = *(const ushort8*)(p1l + (kb) * 512); \
    } while (0)
#define STEPG(G, kb, kbn, DO) do { \
        bf16x8 ah  = __builtin_bit_cast(bf16x8, *(const ushort8*)(smem + (kb) * 1024 + lane * 16)); \
        bf16x8 alo = __builtin_bit_cast(bf16x8, *(const ushort8*)(smem + 16384 + (kb) * 1024 + lane * 16)); \
        bf16x8 b0h = __builtin_bit_cast(bf16x8, r##G##0); \
        bf16x8 b0l = __builtin_bit_cast(bf16x8, r##G##1); \
        bf16x8 c1h = __builtin_bit_cast(bf16x8, r##G##2); \
        bf16x8 c1l = __builtin_bit_cast(bf16x8, r##G##3); \
        A0 = MFMA(ah, b0h, A0); A0 = MFMA(ah, b0l, A0); A0 = MFMA(alo, b0h, A0); \
        A1 = MFMA(ah, c1h, A1); A1 = MFMA(ah, c1l, A1); A1 = MFMA(alo, c1h, A1); \
        if (DO) LOADG(G, kbn); \
    } while (0)
    LOADG(0, 0); LOADG(1, 1); LOADG(2, 2); LOADG(3, 3);
    STEPG(0, 0, 4, 1);  STEPG(1, 1, 5, 1);  STEPG(2, 2, 6, 1);  STEPG(3, 3, 7, 1);
    STEPG(0, 4, 8, 1);  STEPG(1, 5, 9, 1);  STEPG(2, 6, 10, 1); STEPG(3, 7, 11, 1);
    STEPG(0, 8, 12, 1); STEPG(1, 9, 13, 1); STEPG(2, 10, 14, 1);STEPG(3, 11, 15, 1);
    STEPG(0, 12, 0, 0); STEPG(1, 13, 0, 0); STEPG(2, 14, 0, 0); STEPG(3, 15, 0, 0);
#undef LOADG
#undef STEPG
}

// C/D layout: col = lane&31, row = (r&3) + 8*(r>>2) + 4*(lane>>5)
__device__ __forceinline__ void store_f32f(
    const f32x16& A0, const f32x16& A1, const float* __restrict__ bias, int act,
    float* __restrict__ Out, const int nb0, const int lane, const int rb, const int M)
{
    #pragma unroll
    for (int nt = 0; nt < 2; ++nt) {
        const f32x16& a = nt ? A1 : A0;
        int n = (nb0 + nt) * 32 + (lane & 31);
        float bv = bias ? bias[n] : 0.f;
        #pragma unroll
        for (int r = 0; r < 16; ++r) {
            int row = rb * 32 + (r & 3) + ((r >> 2) << 3) + ((lane >> 5) << 2);
            if (row < M) {
                float v = a[r] + bv;
                if (act) v = gelu_exact(v);
                Out[(size_t)row * 256 + n] = v;
            }
        }
    }
}

// bias + GELU + hi/lo split into pack region, via per-wave pad-33 tbuf transpose
__device__ __forceinline__ void pack_ldsf(
    char* __restrict__ smem, float* __restrict__ tb,
    const f32x16& A0, const f32x16& A1, const float* __restrict__ bias,
    const int nb0, const int lane)
{
    #pragma unroll
    for (int nt = 0; nt < 2; ++nt) {
        const f32x16& a = nt ? A1 : A0;
        int nloc = lane & 31;
        float bv = bias[(nb0 + nt) * 32 + nloc];
        #pragma unroll
        for (int r = 0; r < 16; ++r) {
            int m = (r & 3) + ((r >> 2) << 3) + ((lane >> 5) << 2);
            tb[m * 33 + nloc] = gelu_exact(a[r] + bv);
        }
        asm volatile("s_waitcnt lgkmcnt(0)" ::: "memory");
        #pragma unroll
        for (int qq = 0; qq < 2; ++qq) {
            int c0 = ((lane >> 5) << 3) + (qq << 4);   // local col block 0,8,16,24
            int m2 = lane & 31;
            float vs[8];
            #pragma unroll
            for (int i = 0; i < 8; ++i) vs[i] = tb[m2 * 33 + c0 + i];
            ushort8 hh, ll;
            #pragma unroll
            for (int i = 0; i < 8; ++i) {
                __bf16 hb = (__bf16)vs[i];
                hh[i] = __builtin_bit_cast(unsigned short, hb);
                ll[i] = __builtin_bit_cast(unsigned short, (__bf16)(vs[i] - (float)hb));
            }
            int ng = (nb0 + nt) * 32 + c0;   // global col of first elem
            char* dsth = smem + (ng >> 4) * 1024 + ((ng >> 3) & 1) * 512 + m2 * 16;
            *(ushort8*)dsth = hh;
            *(ushort8*)(dsth + 16384) = ll;
        }
        asm volatile("s_waitcnt lgkmcnt(0)" ::: "memory");  // tb reuse (same wave)
    }
}

// ================= fused node kernel =================
// Block = 32 rows x 256 cols; 4 waves, wave w owns col-subtiles nb0=2w, 2w+1.
// MODE 0: stage 32-row h-pack slab ONCE into LDS, then 5 full-K loops off LDS:
//   K->HBM, Q->HBM, t->packed-in-LDS, M->packed-in-LDS, V->HBM.
// MODE 1: streamed counted-vmcnt pipeline over K=512 (concat h|msg) -> hid;
//   pack hid to LDS; out-loop reads pack, writes final output.
template<int MODE>
__global__ __launch_bounds__(256, 2) void fused_node(
    const unsigned short* __restrict__ Ah, const unsigned short* __restrict__ Al,
    const unsigned short* __restrict__ A2h, const unsigned short* __restrict__ A2l,
    const unsigned short* __restrict__ B1h, const unsigned short* __restrict__ B1l,  // Wk | u_w1
    const unsigned short* __restrict__ B2h, const unsigned short* __restrict__ B2l,  // Wq | u_w2
    const unsigned short* __restrict__ B3h, const unsigned short* __restrict__ B3l,  // m_w1
    const unsigned short* __restrict__ B4h, const unsigned short* __restrict__ B4l,  // m_w2
    const unsigned short* __restrict__ B5h, const unsigned short* __restrict__ B5l,  // Wv
    const float* __restrict__ bias1, const float* __restrict__ bias2,
    int M,
    float* __restrict__ O1, float* __restrict__ O2, float* __restrict__ O3)
{
    extern __shared__ char smem[];
    const int lane = threadIdx.x & 63;
    const int w = threadIdx.x >> 6;
    const int nb0 = w * 2;
    const int rb = blockIdx.x;
    float* tb = (float*)(smem + 32768 + w * 4224);   // per-wave 32 x 33 f32

    if constexpr (MODE == 0) {
        // ---- one-shot stage of the 32-row h slab (32 KB) ----
        #pragma unroll
        for (int i = 0; i < 8; ++i) {
            int u = w * 8 + i, hl = u >> 4, kb = u & 15;
            const unsigned short* srcp = hl ? Al : Ah;
            const unsigned short* g = srcp + ((size_t)(rb * 16 + kb) * 64 + lane) * 8;
            gload_lds16(g, smem + hl * 16384 + kb * 1024);
        }
        asm volatile("s_waitcnt vmcnt(0)" ::: "memory");
        __builtin_amdgcn_s_barrier();

        { f32x16 a0 = {}, a1 = {};
          gemm_lds256(smem, lane, nb0, B1h, B1l, a0, a1);
          store_f32f(a0, a1, nullptr, 0, O1, nb0, lane, rb, M); }   // K = h@Wk
        { f32x16 a0 = {}, a1 = {};
          gemm_lds256(smem, lane, nb0, B2h, B2l, a0, a1);
          store_f32f(a0, a1, nullptr, 0, O2, nb0, lane, rb, M); }   // Q = h@Wq
        f32x16 t0 = {}, t1 = {};
        gemm_lds256(smem, lane, nb0, B3h, B3l, t0, t1);             // t = h@m_w1
        __syncthreads();                                            // all A reads done
        pack_ldsf(smem, tb, t0, t1, bias1, nb0, lane);              // gelu(t+b1) -> LDS
        __syncthreads();
        f32x16 m0 = {}, m1 = {};
        gemm_lds256(smem, lane, nb0, B4h, B4l, m0, m1);             // M = t@m_w2
        __syncthreads();
        pack_ldsf(smem, tb, m0, m1, bias2, nb0, lane);              // gelu(M+b2) -> LDS
        __syncthreads();
        { f32x16 a0 = {}, a1 = {};
          gemm_lds256(smem, lane, nb0, B5h, B5l, a0, a1);
          store_f32f(a0, a1, nullptr, 0, O3, nb0, lane, rb, M); }   // V = M@Wv
    } else {
        // ---- phase 2: streamed hid over K=512 (counted-vmcnt, 3-buffer) ----
        auto stage_one = [&](int bufn, int st, int u) {
            int hl = u >> 2, kb = u & 3;
            int kbg = st * 4 + kb;
            const unsigned short* srcp; int kba = kbg;
            if (kbg >= 16) { kba = kbg - 16; srcp = hl ? A2l : A2h; }
            else           { srcp = hl ? Al : Ah; }
            const unsigned short* g = srcp + ((size_t)(rb * 16 + kba) * 64 + lane) * 8;
            gload_lds16(g, smem + bufn * 8192 + (hl * 4 + kb) * 1024);
        };
        stage_one(0, 0, w * 2); stage_one(0, 0, w * 2 + 1);
        stage_one(1, 1, w * 2); stage_one(1, 1, w * 2 + 1);
        asm volatile("s_waitcnt vmcnt(2)" ::: "memory");
        __builtin_amdgcn_s_barrier();

        // u_w1 pack base (KB=32): (nb*32 + kbg)*512 + lane*8 ushorts
        const unsigned short* u0h = B1h + (size_t)nb0 * 16384 + lane * 8;
        const unsigned short* u0l = B1l + (size_t)nb0 * 16384 + lane * 8;
        const unsigned short* u1h = u0h + 16384;
        const unsigned short* u1l = u0l + 16384;

        f32x16 h0 = {}, h1 = {};
        for (int st = 0; st < 8; ++st) {
            if (st) {
                // per iter: 16 B-loads + 2 staging = 18 newer than stage st's loads
                asm volatile("s_waitcnt vmcnt(18)" ::: "memory");
                __builtin_amdgcn_s_barrier();
            }
            const int buf = st % 3;
            const int kg0 = st * 4;
            ushort8 q00, q01, q02, q03, q10, q11, q12, q13;
            ushort8 q20, q21, q22, q23, q30, q31, q32, q33;
#define LOADQ(G, kb) do { \
            q##G##0 = *(const ushort8*)(u0h + (size_t)(kg0 + (kb)) * 512); \
            q##G##1 = *(const ushort8*)(u0l + (size_t)(kg0 + (kb)) * 512); \
            q##G##2 = *(const ushort8*)(u1h + (size_t)(kg0 + (kb)) * 512); \
            q##G##3 = *(const ushort8*)(u1l + (size_t)(kg0 + (kb)) * 512); \
    } while (0)
            LOADQ(0, 0); LOADQ(1, 1); LOADQ(2, 2); LOADQ(3, 3);
            {
                int bufn = (st + 2) % 3;
                int stc = (st + 2 < 8) ? (st + 2) : 7;   // tail: harmless reload
                stage_one(bufn, stc, w * 2);
                stage_one(bufn, stc, w * 2 + 1);
            }
#define STEPQ(G, kb) do { \
            bf16x8 ah  = __builtin_bit_cast(bf16x8, \
                *(const ushort8*)(smem + buf * 8192 + (kb) * 1024 + lane * 16)); \
            bf16x8 alo = __builtin_bit_cast(bf16x8, \
                *(const ushort8*)(smem + buf * 8192 + (4 + (kb)) * 1024 + lane * 16)); \
            bf16x8 b0h = __builtin_bit_cast(bf16x8, q##G##0); \
            bf16x8 b0l = __builtin_bit_cast(bf16x8, q##G##1); \
            bf16x8 c1h = __builtin_bit_cast(bf16x8, q##G##2); \
            bf16x8 c1l = __builtin_bit_cast(bf16x8, q##G##3); \
            h0 = MFMA(ah, b0h, h0); h0 = MFMA(ah, b0l, h0); h0 = MFMA(alo, b0h, h0); \
            h1 = MFMA(ah, c1h, h1); h1 = MFMA(ah, c1l, h1); h1 = MFMA(alo, c1h, h1); \
    } while (0)
            STEPQ(0, 0); STEPQ(1, 1); STEPQ(2, 2); STEPQ(3, 3);
#undef LOADQ
#undef STEPQ
        }
        asm volatile("s_waitcnt vmcnt(0)" ::: "memory");   // drain stray prefetches
        __builtin_amdgcn_s_barrier();

        pack_ldsf(smem, tb, h0, h1, bias1, nb0, lane);     // gelu(hid+u_b1) -> LDS
        __syncthreads();
        { f32x16 o0 = {}, o1 = {};
          gemm_lds256(smem, lane, nb0, B2h, B2l, o0, o1);
          store_f32f(o0, o1, bias2, 1, O3, nb0, lane, rb, M); }  // out = gelu(hid@u_w2+u_b2)
    }
}

// ================= host =================
extern "C" void kernel_launch(void* const* d_in, const int* in_sizes, int n_in,
                              void* d_out, int out_size, void* d_ws, size_t ws_size,
                              hipStream_t stream) {
    const float* inv_h    = (const float*)d_in[0];
    const float* asset_h  = (const float*)d_in[1];
    const float* inv_nw   = (const float*)d_in[2];
    const float* asset_nw = (const float*)d_in[3];
    const float* m_w1 = (const float*)d_in[4];
    const float* m_b1 = (const float*)d_in[5];
    const float* m_w2 = (const float*)d_in[6];
    const float* m_b2 = (const float*)d_in[7];
    const float* Wq   = (const float*)d_in[8];
    const float* Wk   = (const float*)d_in[9];
    const float* Wv   = (const float*)d_in[10];
    const float* u_w1 = (const float*)d_in[11];
    const float* u_b1 = (const float*)d_in[12];
    const float* u_w2 = (const float*)d_in[13];
    const float* u_b2 = (const float*)d_in[14];
    const int* etgt  = (const int*)d_in[15];
    const int* esrc  = (const int*)d_in[16];

    const int I = in_sizes[0] / 256;
    const int A = in_sizes[1] / 256;
    const int E = in_sizes[15];
    const int RBI = (I + 31) >> 5;
    const int RBA = (A + 31) >> 5;

    float* out_inv   = (float*)d_out;
    float* out_asset = (float*)d_out + (size_t)I * 256;

    char* wsp = (char*)d_ws;
    size_t off = 0;
    auto alloc = [&](size_t bytes) -> char* {
        char* p = wsp + off;
        off += (bytes + 255) & ~(size_t)255;
        return p;
    };

    const size_t ipackHalf = (size_t)RBI * 16384;  // bytes per half (hi or lo)
    const size_t apackHalf = (size_t)RBA * 16384;

    unsigned short* invP_h = (unsigned short*)alloc(ipackHalf);
    unsigned short* invP_l = (unsigned short*)alloc(ipackHalf);
    unsigned short* astP_h = (unsigned short*)alloc(apackHalf);
    unsigned short* astP_l = (unsigned short*)alloc(apackHalf);
    // K_i f32; later overlaid by msgP_i (K_i dead after dir-2 attn)
    char* KfI_raw = alloc(2 * ipackHalf);
    float* KfI = (float*)KfI_raw;
    unsigned short* msgI_h = (unsigned short*)KfI_raw;
    unsigned short* msgI_l = (unsigned short*)(KfI_raw + ipackHalf);
    float* QfI = (float*)alloc((size_t)I * 1024);
    float* VfI = (float*)alloc((size_t)I * 1024);
    float* KfA = (float*)alloc((size_t)A * 1024);
    float* QfA = (float*)alloc((size_t)A * 1024);
    float* VfA = (float*)alloc((size_t)A * 1024);
    unsigned short* msgA_h = (unsigned short*)alloc(apackHalf);
    unsigned short* msgA_l = (unsigned short*)alloc(apackHalf);
    float* scbuf = (float*)alloc((size_t)E * 4 * 4);
    int* cnt_i  = (int*)alloc((size_t)I * 4);
    int* cnt_a  = (int*)alloc((size_t)A * 4);
    int* offs_i = (int*)alloc((size_t)(I + 1) * 4);
    int* offs_a = (int*)alloc((size_t)(A + 1) * 4);
    int* gsrc_i = (int*)alloc((size_t)E * 4);
    int* gsrc_a = (int*)alloc((size_t)E * 4);
    float* glw_i = (float*)alloc((size_t)E * 4);
    float* glw_a = (float*)alloc((size_t)E * 4);
    int* bsum_i = (int*)alloc(256 * 4);
    int* bsum_a = (int*)alloc(256 * 4);

    // weight packs: 0=m_w1 1=m_w2 2=Wq 3=Wk 4=Wv 5=u_w1 6=u_w2
    PrepArgs pa;
    const float* wsrc[7] = {m_w1, m_w2, Wq, Wk, Wv, u_w1, u_w2};
    const int    wK[7]   = {256, 256, 256, 256, 256, 512, 256};
    unsigned short* wph[7];
    unsigned short* wpl[7];
    pa.off[0] = 0;
    for (int i = 0; i < 7; ++i) {
        size_t slots = (size_t)(wK[i] >> 4) * 8 * 64;
        wph[i] = (unsigned short*)alloc(slots * 16);
        wpl[i] = (unsigned short*)alloc(slots * 16);
        pa.src[i] = wsrc[i];
        pa.hi[i] = wph[i];
        pa.lo[i] = wpl[i];
        pa.K[i] = wK[i];
        pa.off[i + 1] = pa.off[i] + (int)slots;
    }

    const int nbI = (I + 255) / 256;
    const int nbA = (A + 255) / 256;
    const int nbE = (E + 255) / 256;

    // ---- operand prep ----
    hipLaunchKernelGGL(prep_w, dim3((pa.off[7] + 255) / 256), dim3(256), 0, stream, pa);
    hipLaunchKernelGGL(pack_rows, dim3((RBI * 1024 + 255) / 256), dim3(256), 0, stream,
                       inv_h, invP_h, invP_l, I, RBI);
    hipLaunchKernelGGL(pack_rows, dim3((RBA * 1024 + 255) / 256), dim3(256), 0, stream,
                       asset_h, astP_h, astP_l, A, RBA);

    // ---- CSR build ----
    hipMemsetAsync(cnt_i, 0, (size_t)I * 4, stream);
    hipMemsetAsync(cnt_a, 0, (size_t)A * 4, stream);
    hipLaunchKernelGGL(count_kernel, dim3(nbE), dim3(256), 0, stream,
                       etgt, esrc, cnt_i, cnt_a, E);
    hipLaunchKernelGGL(scan_block, dim3(nbI), dim3(256), 0, stream, cnt_i, offs_i, bsum_i, I);
    hipLaunchKernelGGL(scan_block, dim3(nbA), dim3(256), 0, stream, cnt_a, offs_a, bsum_a, A);
    hipLaunchKernelGGL(scan_bsum, dim3(1), dim3(256), 0, stream, bsum_i, nbI);
    hipLaunchKernelGGL(scan_bsum, dim3(1), dim3(256), 0, stream, bsum_a, nbA);
    hipLaunchKernelGGL(add_offs, dim3(nbI), dim3(256), 0, stream, offs_i, cnt_i, bsum_i, I, E);
    hipLaunchKernelGGL(add_offs, dim3(nbA), dim3(256), 0, stream, offs_a, cnt_a, bsum_a, A, E);
    hipLaunchKernelGGL(fill_kernel, dim3(nbE), dim3(256), 0, stream,
                       etgt, esrc, inv_nw, asset_nw, cnt_i, cnt_a,
                       gsrc_i, glw_i, gsrc_a, glw_a, E);

    const unsigned LDSB = 32768 + 4 * 32 * 33 * 4;   // pack + per-wave tbuf = 49664

    // ---- phase 1: per node type, fused K/Q/t/M/V ----
    hipLaunchKernelGGL((fused_node<0>), dim3(RBI), dim3(256), LDSB, stream,
                       invP_h, invP_l, (const unsigned short*)nullptr, (const unsigned short*)nullptr,
                       wph[3], wpl[3],  // Wk
                       wph[2], wpl[2],  // Wq
                       wph[0], wpl[0],  // m_w1
                       wph[1], wpl[1],  // m_w2
                       wph[4], wpl[4],  // Wv
                       m_b1, m_b2, I, KfI, QfI, VfI);
    hipLaunchKernelGGL((fused_node<0>), dim3(RBA), dim3(256), LDSB, stream,
                       astP_h, astP_l, (const unsigned short*)nullptr, (const unsigned short*)nullptr,
                       wph[3], wpl[3], wph[2], wpl[2], wph[0], wpl[0],
                       wph[1], wpl[1], wph[4], wpl[4],
                       m_b1, m_b2, A, KfA, QfA, VfA);

    // ---- attention ----
    hipLaunchKernelGGL(fused_attn, dim3((A + 3) / 4), dim3(256), 0, stream,
                       QfA, KfI, VfI, offs_a, gsrc_a, glw_a, scbuf, msgA_h, msgA_l, A);
    hipLaunchKernelGGL(fused_attn, dim3((I + 3) / 4), dim3(256), 0, stream,
                       QfI, KfA, VfA, offs_i, gsrc_i, glw_i, scbuf, msgI_h, msgI_l, I);

    // ---- phase 2: fused hid->out ----
    hipLaunchKernelGGL((fused_node<1>), dim3(RBA), dim3(256), LDSB, stream,
                       astP_h, astP_l, msgA_h, msgA_l,
                       wph[5], wpl[5],  // u_w1
                       wph[6], wpl[6],  // u_w2
                       (const unsigned short*)nullptr, (const unsigned short*)nullptr,
                       (const unsigned short*)nullptr, (const unsigned short*)nullptr,
                       (const unsigned short*)nullptr, (const unsigned short*)nullptr,
                       u_b1, u_b2, A, (float*)nullptr, (float*)nullptr, out_asset);
    hipLaunchKernelGGL((fused_node<1>), dim3(RBI), dim3(256), LDSB, stream,
                       invP_h, invP_l, msgI_h, msgI_l,
                       wph[5], wpl[5], wph[6], wpl[6],
                       (const unsigned short*)nullptr, (const unsigned short*)nullptr,
                       (const unsigned short*)nullptr, (const unsigned short*)nullptr,
                       (const unsigned short*)nullptr, (const unsigned short*)nullptr,
                       u_b1, u_b2, I, (float*)nullptr, (float*)nullptr, out_inv);
}